// Round 1
// 932.861 us; speedup vs baseline: 1.0659x; 1.0659x over previous
//
#include <hip/hip_runtime.h>
#include <hip/hip_bf16.h>
#include <cstdint>

using bf16 = __hip_bfloat16;
typedef __attribute__((ext_vector_type(8))) short bfrag;   // 8 x bf16 (4 VGPRs)
typedef __attribute__((ext_vector_type(4))) float ffrag;   // 4 x f32 acc

#define DEV __device__ __forceinline__

DEV float wred_sum(float v) {
#pragma unroll
  for (int o = 32; o > 0; o >>= 1) v += __shfl_xor(v, o, 64);
  return v;
}
DEV float bred_sum(float v) {
  __shared__ float r[4];
  int w = threadIdx.x >> 6, l = threadIdx.x & 63;
  v = wred_sum(v);
  __syncthreads();
  if (l == 0) r[w] = v;
  __syncthreads();
  return r[0] + r[1] + r[2] + r[3];
}
DEV float gelu_f(float x) {  // jax.nn.gelu approximate=True
  float x3 = x * x * x;
  return 0.5f * x * (1.0f + tanhf(0.7978845608028654f * (x + 0.044715f * x3)));
}

// ---------------------------------------------------------------- GEMM (NT)
// C[m,n] = sum_k A[m,k] * B[n,k]
struct GemmP {
  const bf16* A; const bf16* A2; const bf16* B; void* C; void* C2;
  const float* bias;
  int K, lda, ldb, ldc, inner, mode, zBshift, c2z, kSplit;
  long sA0, sA1, sB0, sB1, sC0, sC1, sb0, sb1;
  float scale;
};
// modes: 0 bf16 | 1 f32 | 3 bf16 gelu | 4 bf16 elu+1 | 6 bf16 exp(v-16)
static GemmP gp0() {
  GemmP g;
  g.A = nullptr; g.A2 = nullptr; g.B = nullptr; g.C = nullptr; g.C2 = nullptr;
  g.bias = nullptr;
  g.K = 0; g.lda = 0; g.ldb = 0; g.ldc = 0; g.inner = 1; g.mode = 0;
  g.zBshift = 0; g.c2z = -1; g.kSplit = 1 << 30;
  g.sA0 = 0; g.sA1 = 0; g.sB0 = 0; g.sB1 = 0; g.sC0 = 0; g.sC1 = 0;
  g.sb0 = 0; g.sb1 = 0; g.scale = 1.f;
  return g;
}

// LDS bank-conflict swizzle (R5, verified: SQ_LDS_BANK_CONFLICT -> 0):
// row r stores its four 16-B chunks permuted by c ^= (r>>1)&3; staging picks
// the matching global chunk per lane, fragment read applies the same XOR.
template <int BM, int BN, int WM, int WN, bool SPLIT>
__global__ __launch_bounds__(256)
void gemm_nt(GemmP p) {
  constexpr int TI = BM / (WM * 16), TJ = BN / (WN * 16);
  __shared__ bf16 smem[(BM + BN) * 32];
  const int tid = threadIdx.x;
  const int z = blockIdx.z;
  const int z0 = z % p.inner, z1 = z / p.inner;
  const long zB = (long)(z1 >> p.zBshift);
  const bf16* A = p.A + (long)z0 * p.sA0 + (long)z1 * p.sA1;
  const bf16* Bp = p.B + (long)z0 * p.sB0 + zB * p.sB1;
  const int m0 = blockIdx.x * BM, n0 = blockIdx.y * BN;
  const int wave = tid >> 6, lane = tid & 63;
  const int wrow = wave / WN, wcol = wave % WN;
  const int fr = lane & 15, quad = lane >> 4;
  const int swz = (quad ^ ((fr >> 1) & 3)) * 8;
  ffrag acc[TI][TJ] = {};
  constexpr int CH_A = BM * 4;
  constexpr int NIT = (BM + BN) * 4 / 256;
  for (int k0 = 0; k0 < p.K; k0 += 32) {
    const bf16* Asrc = A;
    int kc = k0;
    if constexpr (SPLIT) {
      if (k0 >= p.kSplit) { Asrc = p.A2; kc = k0 - p.kSplit; }
    }
#pragma unroll
    for (int it = 0; it < NIT; ++it) {
      int idx = it * 256 + tid;
      const bf16* g;
      if (idx < CH_A) {
        int r = idx >> 2, c = (idx & 3) ^ ((idx >> 3) & 3);
        g = Asrc + (long)(m0 + r) * p.lda + kc + c * 8;
      } else {
        int j = idx - CH_A;
        int r = j >> 2, c = (j & 3) ^ ((j >> 3) & 3);
        g = Bp + (long)(n0 + r) * p.ldb + k0 + c * 8;
      }
      __builtin_amdgcn_global_load_lds(
          (const __attribute__((address_space(1))) void*)g,
          (__attribute__((address_space(3))) void*)(smem + idx * 8), 16, 0, 0);
    }
    __syncthreads();
    bfrag af[TI], bfb[TJ];
#pragma unroll
    for (int t = 0; t < TI; ++t)
      af[t] = *(const bfrag*)(smem + ((wrow * (TI * 16) + t * 16 + fr) * 32 + swz));
#pragma unroll
    for (int t = 0; t < TJ; ++t)
      bfb[t] = *(const bfrag*)(smem + (BM * 32 + (wcol * (TJ * 16) + t * 16 + fr) * 32 + swz));
#pragma unroll
    for (int ti = 0; ti < TI; ++ti)
#pragma unroll
      for (int tj = 0; tj < TJ; ++tj)
        acc[ti][tj] = __builtin_amdgcn_mfma_f32_16x16x32_bf16(af[ti], bfb[tj], acc[ti][tj], 0, 0, 0);
    __syncthreads();
  }
  const int mbase = m0 + wrow * (TI * 16), nbase = n0 + wcol * (TJ * 16);
  void* Cb = p.C;
  long zc = (long)z0 * p.sC0 + (long)z1 * p.sC1;
  if (z == p.c2z) { Cb = p.C2; zc = 0; }
  const long zb = (long)z0 * p.sb0 + zB * p.sb1;
#pragma unroll
  for (int ti = 0; ti < TI; ++ti) {
#pragma unroll
    for (int tj = 0; tj < TJ; ++tj) {
#pragma unroll
      for (int r = 0; r < 4; ++r) {
        int m = mbase + ti * 16 + quad * 4 + r;
        int n = nbase + tj * 16 + fr;
        float v = acc[ti][tj][r] * p.scale;
        if (p.bias) v += p.bias[zb + n];
        long ci = zc + (long)m * p.ldc + n;
        if (p.mode == 0) ((bf16*)Cb)[ci] = __float2bfloat16(v);
        else if (p.mode == 1) ((float*)Cb)[ci] = v;
        else if (p.mode == 3) ((bf16*)Cb)[ci] = __float2bfloat16(gelu_f(v));
        else if (p.mode == 4) ((bf16*)Cb)[ci] = __float2bfloat16(v > 0.f ? v + 1.f : __expf(v));
        else ((bf16*)Cb)[ci] = __float2bfloat16(__expf(v - 16.f));
      }
    }
  }
}

// cfg 0: 128x128 | 1: 128x64 | 2: 64x64 | 3: 64x64 split-A
static void launch_gemm(hipStream_t st, int cfg, int M, int N, int batch, const GemmP& g) {
  dim3 bs(256);
  if (cfg == 0)      gemm_nt<128, 128, 2, 2, false><<<dim3(M / 128, N / 128, batch), bs, 0, st>>>(g);
  else if (cfg == 1) gemm_nt<128, 64, 2, 2, false><<<dim3(M / 128, N / 64, batch), bs, 0, st>>>(g);
  else if (cfg == 2) gemm_nt<64, 64, 2, 2, false><<<dim3(M / 64, N / 64, batch), bs, 0, st>>>(g);
  else               gemm_nt<64, 64, 2, 2, true><<<dim3(M / 64, N / 64, batch), bs, 0, st>>>(g);
}

// ---------------------------------------------------------------- GEMM 256x256 / BK=64
// 8-wave (2M x 4N) double-buffered schedule with counted vmcnt (T3+T4+T5):
// - raw s_barrier + asm s_waitcnt vmcnt(NL): next tile's 8 staging loads stay
//   in flight across the barrier (never drain to 0 in steady state)
// - chunk swizzle cs = c ^ (r&7): uniform 8 lanes/16B-chunk on ds_read_b128
//   (conflict-free); inverse permutation applied on the per-lane GLOBAL source
//   since global_load_lds writes LDS linearly (both-sides-or-neither rule)
// - staging pointers advance +64 elem/tile (address math amortized)
// - s_setprio(1) around each MFMA phase (4 phases x 16 MFMA per tile)
// mode 0 (bf16 + bias + c2z) only. Requires K % 64 == 0, K >= 128,
// M % 256 == 0, N % 256 == 0.
template <int BM2, int BN2>
__global__ __launch_bounds__(512)
void gemm_nt8(GemmP p) {
  constexpr int TI = BM2 / 32;              // m-frags per wave (8)
  constexpr int TJ = BN2 / 64;              // n-frags per wave (4)
  constexpr int BUFEL = (BM2 + BN2) * 64;   // elems per LDS buffer
  constexpr int NLA = BM2 / 64;             // A loads/thread/tile (4)
  constexpr int NLB = BN2 / 64;             // B loads/thread/tile (4)
  constexpr int NL = NLA + NLB;             // 8
  __shared__ __align__(16) bf16 smem[2 * BUFEL];   // 128 KiB
  const int tid = threadIdx.x;
  const int z = blockIdx.z;
  const int z0 = z % p.inner, z1 = z / p.inner;
  const long zB = (long)(z1 >> p.zBshift);
  const bf16* A = p.A + (long)z0 * p.sA0 + (long)z1 * p.sA1;
  const bf16* Bp = p.B + (long)z0 * p.sB0 + zB * p.sB1;
  const int m0 = blockIdx.x * BM2, n0 = blockIdx.y * BN2;
  const int wave = tid >> 6, lane = tid & 63;
  const int wrow = wave >> 2, wcol = wave & 3;          // 2 x 4 waves
  const int fr = lane & 15, quad = lane >> 4;

  // per-thread staging sources (fixed row/chunk; +64 elems per K-tile)
  const bf16* gsrc[NL];
  int loff[NL];
#pragma unroll
  for (int i = 0; i < NLA; ++i) {
    int idx = i * 512 + tid;
    int r = idx >> 3, cs = idx & 7, c = cs ^ (r & 7);
    gsrc[i] = A + (long)(m0 + r) * p.lda + c * 8;
    loff[i] = idx * 8;
  }
#pragma unroll
  for (int i = 0; i < NLB; ++i) {
    int j = i * 512 + tid;
    int r = j >> 3, cs = j & 7, c = cs ^ (r & 7);
    gsrc[NLA + i] = Bp + (long)(n0 + r) * p.ldb + c * 8;
    loff[NLA + i] = BM2 * 64 + j * 8;
  }
  auto stage = [&](int buf) {
#pragma unroll
    for (int i = 0; i < NL; ++i) {
      __builtin_amdgcn_global_load_lds(
          (const __attribute__((address_space(1))) void*)gsrc[i],
          (__attribute__((address_space(3))) void*)(smem + buf * BUFEL + loff[i]),
          16, 0, 0);
      gsrc[i] += 64;
    }
  };

  // fragment read offsets: row r's chunk c sits at cs = c ^ (r&7); here
  // r & 7 == fr & 7 for every fragment row (ti*16, wrow*128 are 0 mod 8)
  const int cs0 = (quad ^ (fr & 7)) * 8;           // kk = 0
  const int cs1 = ((quad ^ (fr & 7)) ^ 4) * 8;     // kk = 1
  const int aBase = (wrow * (BM2 / 2) + fr) * 64;
  const int bBase = BM2 * 64 + (wcol * (TJ * 16) + fr) * 64;

  ffrag acc[TI][TJ] = {};
  const int NT = p.K >> 6;
  stage(0);
  stage(1);
  for (int kt = 0; kt < NT; ++kt) {
    const int cur = kt & 1;
    const bf16* sb = smem + cur * BUFEL;
    if (kt + 1 < NT) asm volatile("s_waitcnt vmcnt(%0)" ::"n"(NL) : "memory");
    else             asm volatile("s_waitcnt vmcnt(0)" ::: "memory");
    __builtin_amdgcn_s_barrier();      // all waves: tile kt fully resident
    asm volatile("" ::: "memory");
    bfrag b0[TJ], b1[TJ];
#pragma unroll
    for (int tj = 0; tj < TJ; ++tj) {
      b0[tj] = *(const bfrag*)(sb + bBase + tj * 1024 + cs0);
      b1[tj] = *(const bfrag*)(sb + bBase + tj * 1024 + cs1);
    }
#pragma unroll
    for (int ph = 0; ph < 4; ++ph) {
      __builtin_amdgcn_s_setprio(1);
#pragma unroll
      for (int t2 = 0; t2 < TI / 4; ++t2) {
        const int ti = ph * (TI / 4) + t2;
        bfrag a0 = *(const bfrag*)(sb + aBase + ti * 1024 + cs0);
        bfrag a1 = *(const bfrag*)(sb + aBase + ti * 1024 + cs1);
#pragma unroll
        for (int tj = 0; tj < TJ; ++tj) {
          acc[ti][tj] = __builtin_amdgcn_mfma_f32_16x16x32_bf16(a0, b0[tj], acc[ti][tj], 0, 0, 0);
          acc[ti][tj] = __builtin_amdgcn_mfma_f32_16x16x32_bf16(a1, b1[tj], acc[ti][tj], 0, 0, 0);
        }
      }
      __builtin_amdgcn_s_setprio(0);
    }
    asm volatile("" ::: "memory");
    __builtin_amdgcn_s_barrier();      // all waves done reading buf cur
    asm volatile("" ::: "memory");
    if (kt + 2 < NT) stage(cur);       // overwrite buf cur with tile kt+2
  }

  const int mbase = m0 + wrow * (BM2 / 2), nbase = n0 + wcol * (TJ * 16);
  void* Cb = p.C;
  long zc = (long)z0 * p.sC0 + (long)z1 * p.sC1;
  if (z == p.c2z) { Cb = p.C2; zc = 0; }
  const long zb = (long)z0 * p.sb0 + zB * p.sb1;
#pragma unroll
  for (int ti = 0; ti < TI; ++ti) {
#pragma unroll
    for (int tj = 0; tj < TJ; ++tj) {
#pragma unroll
      for (int r = 0; r < 4; ++r) {
        int m = mbase + ti * 16 + quad * 4 + r;
        int n = nbase + tj * 16 + fr;
        float v = acc[ti][tj][r] * p.scale;
        if (p.bias) v += p.bias[zb + n];
        ((bf16*)Cb)[zc + (long)m * p.ldc + n] = __float2bfloat16(v);
      }
    }
  }
}

static void launch_gemm8(hipStream_t st, int M, int N, int batch, const GemmP& g) {
  gemm_nt8<256, 256><<<dim3(M / 256, N / 256, batch), dim3(512), 0, st>>>(g);
}

// ---------------------------------------------------------------- prep (all weight transposes)
// grid (32, 64, 42); src[R][C] f32 -> dst[C][R] bf16, demuxed on z
__global__ void prep_k(const float* w_qkvo, const float* sub_w1, const float* sub_w2,
                       const float* conv_pw, const float* fus_w, const float* r1_w1,
                       const float* r2_w1, const float* phi_w, const float* psi_w,
                       const float* phi_b, const float* psi_b,
                       bf16* wt, bf16* fuswt, bf16* r1w1t, bf16* r2w1t,
                       bf16* phiwt, bf16* psiwt, float* phipsib, bf16* vtp1) {
  int z = blockIdx.z;
  int bx = blockIdx.x, by = blockIdx.y;
  int tx = threadIdx.x & 31, ty = threadIdx.x >> 5;
  const float* src; bf16* dst; int R, C;
  if (z < 33) {
    if (by >= 32) return;
    src = z < 16 ? w_qkvo + (long)z * 1048576
        : z < 24 ? sub_w1 + (long)(z - 16) * 1048576
        : z < 32 ? sub_w2 + (long)(z - 24) * 1048576
                 : conv_pw;
    dst = wt + (long)z * 1048576; R = 1024; C = 1024;
  } else if (z == 33) {
    src = fus_w; dst = fuswt; R = 2048; C = 1024;
  } else if (z == 34) {
    if (bx >= 16 || by >= 32) return;
    src = r1_w1; dst = r1w1t; R = 1024; C = 512;
  } else if (z < 39) {
    if (bx >= 8 || by >= 32) return;
    src = r2_w1 + (long)(z - 35) * 262144; dst = r2w1t + (long)(z - 35) * 262144;
    R = 1024; C = 256;
  } else if (z < 41) {
    if (bx >= 8 || by >= 2) return;
    src = (z == 39) ? phi_w : psi_w; dst = (z == 39) ? phiwt : psiwt; R = 64; C = 256;
  } else {
    if (by == 0) {  // ones row (performer ksum trick): slice bx of VTP1
      for (int c = threadIdx.x; c < 1024; c += 256)
        vtp1[(long)bx * 131072 + 65536 + c] = __float2bfloat16(1.0f);
    } else if (by == 1 && bx == 0) {
      for (int i = threadIdx.x; i < 512; i += 256)
        phipsib[i] = i < 256 ? phi_b[i] : psi_b[i - 256];
    }
    return;
  }
  __shared__ float t[32][33];
  int c0 = bx * 32, r0 = by * 32;
#pragma unroll
  for (int i = 0; i < 32; i += 8)
    t[ty + i][tx] = src[(long)(r0 + ty + i) * C + c0 + tx];
  __syncthreads();
#pragma unroll
  for (int i = 0; i < 32; i += 8)
    dst[(long)(c0 + ty + i) * R + r0 + tx] = __float2bfloat16(t[tx][ty + i]);
}

// per-row: x->bf16, depthwise conv, token-importance dot — one x pass
__global__ void xprep_k(const float* x, const float* dw, const float* spw, const float* spb,
                        bf16* xb, bf16* t1, float* tokimp) {
  long row = blockIdx.x;                 // 2048 rows
  int s = (int)(row & 1023);
  int tid = threadIdx.x;
  const float* xr = x + row * 1024;
  float dot = 0.f;
#pragma unroll
  for (int i = 0; i < 4; ++i) {
    int d = tid + i * 256;
    float xv = xr[d];
    xb[row * 1024 + d] = __float2bfloat16(xv);
    float a = xv * dw[1024 + d];
    if (s > 0) a += xr[d - 1024] * dw[d];
    if (s < 1023) a += xr[d + 1024] * dw[2048 + d];
    t1[row * 1024 + d] = __float2bfloat16(a);
    dot += xv * spw[d];
  }
  float tot = bred_sum(dot);
  if (tid == 0) tokimp[row] = tot + spb[0];
}

// bf16 strided [z](R x C, row stride rs) -> bf16 out + z*ldz, out[c*R + r]
__global__ void transpose_bf16_k(const bf16* in, bf16* outp, int R, int C, int rs,
                                 int inner, int inner2, long is0, long is1, long is2,
                                 long ldz) {
  __shared__ bf16 t[32][33];
  int z = blockIdx.z;
  int z0 = z % inner; int zr = z / inner;
  int z1 = zr % inner2; int z2 = zr / inner2;
  long zo = (long)z0 * is0 + (long)z1 * is1 + (long)z2 * is2;
  int c0 = blockIdx.x * 32, r0 = blockIdx.y * 32;
  int tx = threadIdx.x & 31, ty = threadIdx.x >> 5;
#pragma unroll
  for (int i = 0; i < 32; i += 8)
    t[ty + i][tx] = in[zo + (long)(r0 + ty + i) * rs + c0 + tx];
  __syncthreads();
  long ob = (long)z * ldz;
#pragma unroll
  for (int i = 0; i < 32; i += 8)
    outp[ob + (long)(c0 + ty + i) * R + r0 + tx] = t[tx][ty + i];
}

// ones row 64 of 64 slices [128][1024] (attention denominator trick)
__global__ void vtones_k(bf16* vt) {
  int i = blockIdx.x * 256 + threadIdx.x;
  int z = i >> 10, c = i & 1023;
  vt[(long)z * 131072 + 65536 + c] = __float2bfloat16(1.0f);
}

// out[((b*1024+s)*1024) + h*64 + n] = in[(h+16b)*131072 + s*128 + n] / (in[..64]+eps)
__global__ void norm_k(const bf16* in, bf16* outp, float eps) {
  int r = blockIdx.x * 4 + (threadIdx.x >> 6);   // z*1024 + s
  int n = threadIdx.x & 63;
  int z = r >> 10, s = r & 1023;
  int h = z & 15, b = z >> 4;
  const bf16* ip = in + (long)r * 128;
  float den = __bfloat162float(ip[64]) + eps;
  float v = __bfloat162float(ip[n]);
  outp[((long)(b * 1024 + s) * 1024) + h * 64 + n] = __float2bfloat16(v / den);
}

// LN + act, single global read (register cache), N <= 1024
__global__ void ln_act_k(const void* in, const float* gamma, const float* beta,
                         bf16* outp, int N, int act, int rows_per_seg, int in_bf16) {
  long row = blockIdx.x;
  int tid = threadIdx.x;
  const bf16* ib = (const bf16*)in;
  const float* iff = (const float*)in;
  float vc[4];
  float ls = 0.f;
  int i = 0;
  for (int c = tid; c < N; c += 256, ++i) {
    float v = in_bf16 ? __bfloat162float(ib[row * N + c]) : iff[row * N + c];
    vc[i] = v; ls += v;
  }
  float mean = bred_sum(ls) / N;
  float lv = 0.f;
  i = 0;
  for (int c = tid; c < N; c += 256, ++i) { float d = vc[i] - mean; lv += d * d; }
  float rstd = rsqrtf(bred_sum(lv) / N + 1e-5f);
  long go = (row / rows_per_seg) * (long)N;
  const float* gp = gamma + go;
  const float* bp = beta + go;
  i = 0;
  for (int c = tid; c < N; c += 256, ++i) {
    float v = (vc[i] - mean) * rstd * gp[c] + bp[c];
    v = act ? gelu_f(v) : fmaxf(v, 0.f);
    outp[row * N + c] = __float2bfloat16(v);
  }
}

__global__ void topk_k(const float* timp, int* outp) {
  __shared__ float vals[1024];
  __shared__ float wv[4];
  __shared__ int wi[4];
  int b = blockIdx.x, tid = threadIdx.x;
  for (int c = tid; c < 1024; c += 256) vals[c] = timp[b * 1024 + c];
  __syncthreads();
  for (int t = 0; t < 10; ++t) {
    float bv = -3.0e38f; int bi = 1 << 30;
    for (int c = tid; c < 1024; c += 256) {
      float v = vals[c];
      if (v > bv || (v == bv && c < bi)) { bv = v; bi = c; }
    }
#pragma unroll
    for (int o = 32; o > 0; o >>= 1) {
      float ov = __shfl_xor(bv, o, 64); int oi = __shfl_xor(bi, o, 64);
      if (ov > bv || (ov == bv && oi < bi)) { bv = ov; bi = oi; }
    }
    int w = tid >> 6, l = tid & 63;
    if (l == 0) { wv[w] = bv; wi[w] = bi; }
    __syncthreads();
    if (tid == 0) {
      float fv = wv[0]; int fi = wi[0];
      for (int ww = 1; ww < 4; ++ww)
        if (wv[ww] > fv || (wv[ww] == fv && wi[ww] < fi)) { fv = wv[ww]; fi = wi[ww]; }
      outp[b * 16 + t] = fi;
      vals[fi] = -3.0e38f;
    }
    __syncthreads();
  }
}

// stage-1 V column sums: 512 blocks, partials [32][16][64]
__global__ void vsum_k(const bf16* v, float* vsump) {
  __shared__ float red[4][64];
  int zz = blockIdx.x;
  int z = zz >> 4, slab = zz & 15;
  int b = z >> 4, h = z & 15;
  const bf16* vp = v + (long)b * 1048576 + h * 64;
  int d = threadIdx.x & 63, sg = threadIdx.x >> 6;
  float s = 0.f;
#pragma unroll
  for (int i = 0; i < 16; ++i) {
    int srow = slab * 64 + sg * 16 + i;
    s += __bfloat162float(vp[(long)srow * 1024 + d]);
  }
  red[sg][d] = s;
  __syncthreads();
  if (sg == 0) vsump[(long)zz * 64 + d] = red[0][d] + red[1][d] + red[2][d] + red[3][d];
}

// expert-0 sparse attention, algebraically reduced
__global__ void sparse_attn_k(const bf16* q, const bf16* k, const bf16* v,
                              const float* vsump, const int* topidx, bf16* merged) {
  __shared__ float kt[10][64], vt[10][64], vs[64], vts[64];
  int z = blockIdx.y, b = z >> 4, h = z & 15;
  int tid = threadIdx.x;
  const int* tix = topidx + b * 16;
  for (int t = tid; t < 640; t += 256) {
    int tt = t >> 6, d = t & 63;
    long src = ((long)b * 1024 + tix[tt]) * 1024 + h * 64 + d;
    kt[tt][d] = __bfloat162float(k[src]);
    vt[tt][d] = __bfloat162float(v[src]);
  }
  if (tid < 64) {
    float s = 0.f;
#pragma unroll
    for (int p = 0; p < 16; ++p) s += vsump[((long)z * 16 + p) * 64 + tid];
    vs[tid] = s;
  }
  __syncthreads();
  if (tid < 64) {
    float s = 0.f;
#pragma unroll
    for (int t = 0; t < 10; ++t) s += vt[t][tid];
    vts[tid] = s;
  }
  __syncthreads();
  int wave = tid >> 6, lane = tid & 63;
  int sq = blockIdx.x * 4 + wave;
  long qi = ((long)b * 1024 + sq) * 1024 + h * 64 + lane;
  float qd = __bfloat162float(q[qi]);
  float sc[10];
#pragma unroll
  for (int t = 0; t < 10; ++t) sc[t] = wred_sum(qd * kt[t][lane]) * 0.125f;
  float m = 0.f;
#pragma unroll
  for (int t = 0; t < 10; ++t) m = fmaxf(m, sc[t]);
  float e[10], se = 0.f;
#pragma unroll
  for (int t = 0; t < 10; ++t) { e[t] = __expf(sc[t] - m); se += e[t]; }
  float em = __expf(-m);
  float Z = 1014.f * em + se;
  float o = em * (vs[lane] - vts[lane]);
#pragma unroll
  for (int t = 0; t < 10; ++t) o += e[t] * vt[t][lane];
  merged[qi] = __float2bfloat16(o / Z);
}

__global__ void router1_k(const bf16* h1, const float* w, const float* bias, float* outp) {
  int row = blockIdx.x * 4 + (threadIdx.x >> 6);
  int l = threadIdx.x & 63;
  const bf16* hp = h1 + (long)row * 512;
  float a0 = 0, a1 = 0, a2 = 0, a3 = 0;
  for (int c = l; c < 512; c += 64) {
    float hv = __bfloat162float(hp[c]);
    const float* wp = w + c * 4;
    a0 += hv * wp[0]; a1 += hv * wp[1]; a2 += hv * wp[2]; a3 += hv * wp[3];
  }
  a0 = wred_sum(a0); a1 = wred_sum(a1); a2 = wred_sum(a2); a3 = wred_sum(a3);
  a0 += bias[0]; a1 += bias[1]; a2 += bias[2]; a3 += bias[3];
  float m = fmaxf(fmaxf(a0, a1), fmaxf(a2, a3));
  float e0 = __expf(a0 - m), e1 = __expf(a1 - m), e2 = __expf(a2 - m), e3 = __expf(a3 - m);
  float inv = 1.f / (e0 + e1 + e2 + e3);
  if (l == 0) {
    float* op = outp + (long)row * 4;
    op[0] = e0 * inv; op[1] = e1 * inv; op[2] = e2 * inv; op[3] = e3 * inv;
  }
}

__global__ void router2_k(const bf16* h2, const float* w, const float* bias, float* outp,
                          int rows_per_seg) {
  int row = blockIdx.x * 4 + (threadIdx.x >> 6);
  int l = threadIdx.x & 63;
  int seg = row / rows_per_seg;
  const float* wp = w + (long)seg * 512;
  const float* bp = bias + (long)seg * 2;
  const bf16* hp = h2 + (long)row * 256;
  float a0 = 0, a1 = 0;
  for (int c = l; c < 256; c += 64) {
    float hv = __bfloat162float(hp[c]);
    a0 += hv * wp[c * 2]; a1 += hv * wp[c * 2 + 1];
  }
  a0 = wred_sum(a0); a1 = wred_sum(a1);
  a0 += bp[0]; a1 += bp[1];
  float m = fmaxf(a0, a1);
  float e0 = __expf(a0 - m), e1 = __expf(a1 - m);
  float inv = 1.f / (e0 + e1);
  if (l == 0) { outp[(long)row * 2] = e0 * inv; outp[(long)row * 2 + 1] = e1 * inv; }
}

// final: out[m,n] = sum_z p1[m][z/2] * p2[z/2][m][z&1] * part[z][m][n]
__global__ void combine_k(const bf16* part, const float* p1, const float* p2, float* outp) {
  long i = (long)blockIdx.x * 256 + threadIdx.x;
  long m = i >> 10;
  float acc = 0.f;
#pragma unroll
  for (int zz = 0; zz < 8; ++zz) {
    int e = zz >> 1, j = zz & 1;
    float w = p1[m * 4 + e] * p2[(long)e * 4096 + m * 2 + j];
    acc += w * __bfloat162float(part[(long)zz * 2097152 + i]);
  }
  outp[i] = acc;
}

// ---------------------------------------------------------------- host
extern "C" void kernel_launch(void* const* d_in, const int* in_sizes, int n_in,
                              void* d_out, int out_size, void* d_ws, size_t ws_size,
                              hipStream_t stream) {
  const float* x = (const float*)d_in[0];
  const float* w_qkvo = (const float*)d_in[1];
  const float* b_qkvo = (const float*)d_in[2];
  const float* sp_w = (const float*)d_in[3];
  const float* sp_b = (const float*)d_in[4];
  const float* phi_w = (const float*)d_in[5];
  const float* phi_b = (const float*)d_in[6];
  const float* psi_w = (const float*)d_in[7];
  const float* psi_b = (const float*)d_in[8];
  const float* conv_dw = (const float*)d_in[9];
  const float* conv_pw = (const float*)d_in[10];
  const float* fus_w = (const float*)d_in[11];
  const float* fus_b = (const float*)d_in[12];
  const float* sub_w1 = (const float*)d_in[13];
  const float* sub_b1 = (const float*)d_in[14];
  const float* sub_g = (const float*)d_in[15];
  const float* sub_be = (const float*)d_in[16];
  const float* sub_w2 = (const float*)d_in[17];
  const float* sub_b2 = (const float*)d_in[18];
  const float* r1_w1 = (const float*)d_in[19];
  const float* r1_b1 = (const float*)d_in[20];
  const float* r1_g = (const float*)d_in[21];
  const float* r1_be = (const float*)d_in[22];
  const float* r1_w2 = (const float*)d_in[23];
  const float* r1_b2 = (const float*)d_in[24];
  const float* r2_w1 = (const float*)d_in[25];
  const float* r2_b1 = (const float*)d_in[26];
  const float* r2_g = (const float*)d_in[27];
  const float* r2_be = (const float*)d_in[28];
  const float* r2_w2 = (const float*)d_in[29];
  const float* r2_b2 = (const float*)d_in[30];
  (void)in_sizes; (void)n_in; (void)ws_size; (void)out_size;

  char* ws = (char*)d_ws;
  size_t off = 0;
  auto take = [&](size_t bytes) { void* p = ws + off; off += (bytes + 255) & ~(size_t)255; return p; };

  const long EL2M = 2097152;  // 2048*1024
  const long EL1M = 1048576;  // 1024*1024

  bf16* XB      = (bf16*)take((size_t)EL2M * 2);
  bf16* WQKVOT  = (bf16*)take((size_t)16 * EL1M * 2);
  bf16* SUBW1T  = (bf16*)take((size_t)8 * EL1M * 2);
  bf16* SUBW2T  = (bf16*)take((size_t)8 * EL1M * 2);
  bf16* CONVPWT = (bf16*)take((size_t)EL1M * 2);
  bf16* FUSWT   = (bf16*)take((size_t)EL2M * 2);
  bf16* R1W1T   = (bf16*)take((size_t)512 * 1024 * 2);
  bf16* R2W1T   = (bf16*)take((size_t)4 * 256 * 1024 * 2);
  bf16* PHIWT   = (bf16*)take((size_t)16384 * 2);
  bf16* PSIWT   = (bf16*)take((size_t)16384 * 2);
  float* PHIPSIB = (float*)take((size_t)512 * 4);
  bf16* QKVB    = (bf16*)take((size_t)12 * EL2M * 2);  // + MERGED4 adjacent -> sub arena
  bf16* MERGED4 = (bf16*)take((size_t)4 * EL2M * 2);
  bf16* VTP1    = (bf16*)take((size_t)32 * 128 * 1024 * 2);  // also performer TNUM
  bf16* EO      = (bf16*)take((size_t)4 * EL2M * 2);
  bf16* T1      = (bf16*)take((size_t)EL2M * 2);       // survives SC phase
  bf16* ARENA   = (bf16*)take((size_t)64 * 1024 * 1024);
  float* PROBS1 = (float*)take((size_t)2048 * 4 * 4);
  float* PROBS2 = (float*)take((size_t)4 * 2048 * 2 * 4);
  float* TOKIMP = (float*)take((size_t)2048 * 4);
  int*   TOPIDX = (int*)take((size_t)2 * 16 * 4);
  float* VSUMP  = (float*)take((size_t)32 * 16 * 64 * 4);

  // ARENA phase 1 (performer):
  bf16* QPHI  = ARENA;                       // [32][1024][256]
  bf16* KPSI  = ARENA + 8388608;             // [32][1024][256]
  bf16* KPSIT = ARENA + 16777216;            // [32][256][1024]
  bf16* KVTX  = ARENA + 25165824;            // [32][128][256] (row64 = ksum)
  // ARENA phase 2 (attention): SC = full 64 MB
  bf16* SC = ARENA;                          // [32][1024][1024]
  // ARENA phase 3 (late, after SC dead):
  bf16* SUB2F = ARENA;                       // [8][2048][1024] bf16 partials
  float* F32TMP = (float*)(ARENA + 16777216);  // 8 MB
  bf16* H1 = ARENA + 20971520;               // [2048][512]
  bf16* H2 = ARENA + 22020096;               // [4*2048][256]
  bf16* AO = ARENA + 24117248;               // [2048][1024]
  bf16* XC = ARENA + 26214400;               // [2048][1024]
  // QKVB slice reuse (dead after sparse/performer phases):
  bf16* TNUM23 = QKVB;                       // slices 0-1: [32][1024][128] PV numerator+den
  bf16* VT23   = QKVB + 2 * EL2M;            // slices 2-5: [64][128][1024] V^T (+ones row 64)
  // sub arena (aliases QKVB+MERGED4, dead by then):
  bf16* SUB1A = QKVB;                        // [8][2048][1024]
  bf16* SUB1B = QKVB + 16777216;             // [8][2048][1024]

  // ---- phase 0: weights + x prep ----
  prep_k<<<dim3(32, 64, 42), 256, 0, stream>>>(w_qkvo, sub_w1, sub_w2, conv_pw, fus_w,
                                               r1_w1, r2_w1, phi_w, psi_w, phi_b, psi_b,
                                               WQKVOT, FUSWT, R1W1T, R2W1T,
                                               PHIWT, PSIWT, PHIPSIB, VTP1);
  xprep_k<<<2048, 256, 0, stream>>>(x, conv_dw, sp_w, sp_b, XB, T1, TOKIMP);

  // ---- QKV for all experts, one batch-12 GEMM (256x256 8-wave pipeline) ----
  {
    GemmP g = gp0();
    g.A = XB; g.lda = 1024;
    g.B = WQKVOT; g.ldb = 1024; g.sB0 = EL1M; g.sB1 = 4 * EL1M;
    g.C = QKVB; g.ldc = 1024; g.sC0 = EL2M; g.sC1 = 3 * EL2M;
    g.bias = b_qkvo; g.sb0 = 1024; g.sb1 = 4096;
    g.K = 1024; g.inner = 3; g.mode = 0;
    launch_gemm8(stream, 2048, 1024, 12, g);
  }

  // ---- expert 0: sparse attention ----
  topk_k<<<2, 256, 0, stream>>>(TOKIMP, TOPIDX);
  vsum_k<<<512, 256, 0, stream>>>(QKVB + 2 * EL2M, VSUMP);
  sparse_attn_k<<<dim3(256, 32), 256, 0, stream>>>(QKVB, QKVB + EL2M, QKVB + 2 * EL2M,
                                                   VSUMP, TOPIDX, MERGED4);

  // ---- expert 1: performer ----
  {  // phi(Q) and psi(K) in one batch-64 GEMM
    GemmP g = gp0();
    g.A = QKVB + 3 * EL2M; g.lda = 1024; g.sA0 = 64; g.sA1 = EL1M;
    g.B = PHIWT; g.ldb = 64; g.sB1 = 16384; g.zBshift = 1;
    g.C = QPHI; g.ldc = 256; g.sC0 = 262144; g.sC1 = 16 * 262144L;
    g.bias = PHIPSIB; g.sb1 = 256;
    g.K = 64; g.inner = 16; g.mode = 4;
    launch_gemm(stream, 2, 1024, 256, 64, g);
  }
  transpose_bf16_k<<<dim3(8, 32, 32), 256, 0, stream>>>(KPSI, KPSIT, 1024, 256, 256,
                                                        32, 1, 262144, 0, 0, 262144);
  transpose_bf16_k<<<dim3(2, 32, 32), 256, 0, stream>>>(QKVB + 5 * EL2M, VTP1, 1024, 64, 1024,
                                                        16, 2, 64, EL1M, 0, 131072);
  {  // KVTX[m,d] = sum_l VTP1[m,l]*KPSIT[d,l]; row 64 = ksum
    GemmP g = gp0();
    g.A = VTP1; g.lda = 1024; g.sA0 = 131072; g.sA1 = 16 * 131072L;
    g.B = KPSIT; g.ldb = 1024; g.sB0 = 262144; g.sB1 = 16 * 262144L;
    g.C = KVTX; g.ldc = 256; g.sC0 = 32768; g.sC1 = 16 * 32768L;
    g.K = 1024; g.inner = 16; g.mode = 0;
    launch_gemm(stream, 2, 128, 256, 32, g);
  }
  {  // num+den: N=128 against KVTX (col 64 = qphi.ksum) -> TNUM (aliases VTP1)
    GemmP g = gp0();
    g.A = QPHI; g.lda = 256; g.sA0 = 262144; g.sA1 = 16 * 262144L;
    g.B = KVTX; g.ldb = 256; g.sB0 = 32768; g.sB1 = 16 * 32768L;
    g.C = VTP1; g.ldc = 128; g.sC0 = 131072; g.sC1 = 16 * 131072L;
    g.K = 256; g.inner = 16; g.mode = 0;
    launch_gemm(stream, 2, 1024, 128, 32, g);
  }
  norm_k<<<8192, 256, 0, stream>>>(VTP1, MERGED4 + EL2M, 1e-8f);

  // ---- V^T (+ones row) for experts 2,3 into dead QKVB slices 2-5 ----
  transpose_bf16_k<<<dim3(2, 32, 64), 256, 0, stream>>>(QKVB + 8 * EL2M, VT23, 1024, 64, 1024,
                                                        16, 2, 64, EL1M, 3 * EL2M, 131072);
  vtones_k<<<256, 256, 0, stream>>>(VT23);

  // ---- experts 2 & 3: softmax attention (exp fused in scores, sum via ones row) ----
  for (int e = 2; e <= 3; ++e) {
    const bf16* q = QKVB + (size_t)(e * 3 + 0) * EL2M;
    const bf16* k = QKVB + (size_t)(e * 3 + 1) * EL2M;
    {  // SC = exp(q k^T * scale - 16)
      GemmP g = gp0();
      g.A = q; g.lda = 1024; g.sA0 = 64; g.sA1 = EL1M;
      g.B = k; g.ldb = 1024; g.sB0 = 64; g.sB1 = EL1M;
      g.C = SC; g.ldc = 1024; g.sC0 = EL1M; g.sC1 = 16 * EL1M;
      g.K = 64; g.inner = 16; g.scale = 0.125f; g.mode = 6;
      launch_gemm(stream, 0, 1024, 1024, 32, g);
    }
    {  // expSC @ [V^T; ones] -> numerator cols 0..63, denominator col 64
      GemmP g = gp0();
      g.A = SC; g.lda = 1024; g.sA0 = EL1M; g.sA1 = 16 * EL1M;
      g.B = VT23 + (size_t)(e - 2) * 32 * 131072; g.ldb = 1024; g.sB0 = 131072; g.sB1 = 16 * 131072L;
      g.C = TNUM23; g.ldc = 128; g.sC0 = 131072; g.sC1 = 16 * 131072L;
      g.K = 1024; g.inner = 16; g.mode = 0;
      launch_gemm(stream, 2, 1024, 128, 32, g);
    }
    norm_k<<<8192, 256, 0, stream>>>(TNUM23, MERGED4 + (size_t)e * EL2M, 0.f);
  }

  // ---- batch-4 output projection (z=3 -> AO), 256x256 pipeline ----
  {
    GemmP g = gp0();
    g.A = MERGED4; g.lda = 1024; g.sA1 = EL2M;
    g.B = WQKVOT + 3 * EL1M; g.ldb = 1024; g.sB1 = 4 * EL1M;
    g.C = EO; g.ldc = 1024; g.sC1 = EL2M;
    g.C2 = AO; g.c2z = 3;
    g.bias = b_qkvo + 3 * 1024; g.sb1 = 4096;
    g.K = 1024; g.mode = 0;
    launch_gemm8(stream, 2048, 1024, 4, g);
  }

  // ---- conv branch + fusion ----
  {
    GemmP g = gp0();
    g.A = T1; g.lda = 1024;
    g.B = CONVPWT; g.ldb = 1024;
    g.C = XC; g.ldc = 1024;
    g.K = 1024; g.mode = 3;
    launch_gemm(stream, 2, 2048, 1024, 1, g);
  }
  {  // fusion: A = [AO | XC], K=2048 (SPLIT variant)
    GemmP g = gp0();
    g.A = AO; g.A2 = XC; g.kSplit = 1024; g.lda = 1024;
    g.B = FUSWT; g.ldb = 2048;
    g.C = EO + 3 * EL2M; g.ldc = 1024;
    g.bias = fus_b; g.K = 2048; g.mode = 0;
    launch_gemm(stream, 3, 2048, 1024, 1, g);
  }

  // ---- routers ----
  {
    GemmP g = gp0();
    g.A = XB; g.lda = 1024;
    g.B = R1W1T; g.ldb = 1024;
    g.C = F32TMP; g.ldc = 512;
    g.bias = r1_b1; g.K = 1024; g.mode = 1;
    launch_gemm(stream, 2, 2048, 512, 1, g);
  }
  ln_act_k<<<2048, 256, 0, stream>>>(F32TMP, r1_g, r1_be, H1, 512, 0, 2048, 0);
  router1_k<<<512, 256, 0, stream>>>(H1, r1_w2, r1_b2, PROBS1);
  {
    GemmP g = gp0();
    g.A = EO; g.lda = 1024; g.sA1 = EL2M;
    g.B = R2W1T; g.ldb = 1024; g.sB1 = 262144;
    g.C = F32TMP; g.ldc = 256; g.sC1 = 2048 * 256;
    g.bias = r2_b1; g.sb1 = 256; g.K = 1024; g.mode = 1;
    launch_gemm(stream, 2, 2048, 256, 4, g);
  }
  ln_act_k<<<8192, 256, 0, stream>>>(F32TMP, r2_g, r2_be, H2, 256, 0, 2048, 0);
  router2_k<<<2048, 256, 0, stream>>>(H2, r2_w2, r2_b2, PROBS2, 2048);

  // ---- sub-experts: batch-8 everything (256x256 pipeline) ----
  {  // sub1: z = j + 2*i
    GemmP g = gp0();
    g.A = EO; g.lda = 1024; g.sA1 = EL2M;
    g.B = SUBW1T; g.ldb = 1024; g.sB0 = EL1M; g.sB1 = 2 * EL1M;
    g.C = SUB1A; g.ldc = 1024; g.sC0 = EL2M; g.sC1 = 2 * EL2M;
    g.bias = sub_b1; g.sb0 = 1024; g.sb1 = 2048;
    g.K = 1024; g.inner = 2; g.mode = 0;
    launch_gemm8(stream, 2048, 1024, 8, g);
  }
  ln_act_k<<<16384, 256, 0, stream>>>(SUB1A, sub_g, sub_be, SUB1B, 1024, 1, 2048, 1);
  {  // sub2 partials (bias folded)
    GemmP g = gp0();
    g.A = SUB1B; g.lda = 1024; g.sA1 = EL2M;
    g.B = SUBW2T; g.ldb = 1024; g.sB1 = EL1M;
    g.C = SUB2F; g.ldc = 1024; g.sC1 = EL2M;
    g.bias = sub_b2; g.sb1 = 1024;
    g.K = 1024; g.mode = 0;
    launch_gemm8(stream, 2048, 1024, 8, g);
  }
  combine_k<<<8192, 256, 0, stream>>>(SUB2F, PROBS1, PROBS2, (float*)d_out);
}

// Round 2
// 913.257 us; speedup vs baseline: 1.0888x; 1.0215x over previous
//
#include <hip/hip_runtime.h>
#include <hip/hip_bf16.h>
#include <cstdint>

using bf16 = __hip_bfloat16;
typedef __attribute__((ext_vector_type(8))) short bfrag;   // 8 x bf16 (4 VGPRs)
typedef __attribute__((ext_vector_type(4))) float ffrag;   // 4 x f32 acc

#define DEV __device__ __forceinline__

DEV float wred_sum(float v) {
#pragma unroll
  for (int o = 32; o > 0; o >>= 1) v += __shfl_xor(v, o, 64);
  return v;
}
DEV float bred_sum(float v) {
  __shared__ float r[4];
  int w = threadIdx.x >> 6, l = threadIdx.x & 63;
  v = wred_sum(v);
  __syncthreads();
  if (l == 0) r[w] = v;
  __syncthreads();
  return r[0] + r[1] + r[2] + r[3];
}
DEV float gelu_f(float x) {  // jax.nn.gelu approximate=True
  float x3 = x * x * x;
  return 0.5f * x * (1.0f + tanhf(0.7978845608028654f * (x + 0.044715f * x3)));
}

// ---------------------------------------------------------------- GEMM (NT)
// C[m,n] = sum_k A[m,k] * B[n,k]
struct GemmP {
  const bf16* A; const bf16* A2; const bf16* B; void* C; void* C2;
  const float* bias;
  int K, lda, ldb, ldc, inner, mode, zBshift, c2z, kSplit;
  long sA0, sA1, sB0, sB1, sC0, sC1, sb0, sb1;
  float scale;
};
// modes: 0 bf16 | 1 f32 | 3 bf16 gelu | 4 bf16 elu+1 | 6 bf16 exp(v-16)
static GemmP gp0() {
  GemmP g;
  g.A = nullptr; g.A2 = nullptr; g.B = nullptr; g.C = nullptr; g.C2 = nullptr;
  g.bias = nullptr;
  g.K = 0; g.lda = 0; g.ldb = 0; g.ldc = 0; g.inner = 1; g.mode = 0;
  g.zBshift = 0; g.c2z = -1; g.kSplit = 1 << 30;
  g.sA0 = 0; g.sA1 = 0; g.sB0 = 0; g.sB1 = 0; g.sC0 = 0; g.sC1 = 0;
  g.sb0 = 0; g.sb1 = 0; g.scale = 1.f;
  return g;
}

// LDS bank-conflict swizzle (R5, verified: SQ_LDS_BANK_CONFLICT -> 0):
// row r stores its four 16-B chunks permuted by c ^= (r>>1)&3; staging picks
// the matching global chunk per lane, fragment read applies the same XOR.
template <int BM, int BN, int WM, int WN, bool SPLIT>
__global__ __launch_bounds__(256)
void gemm_nt(GemmP p) {
  constexpr int TI = BM / (WM * 16), TJ = BN / (WN * 16);
  __shared__ bf16 smem[(BM + BN) * 32];
  const int tid = threadIdx.x;
  const int z = blockIdx.z;
  const int z0 = z % p.inner, z1 = z / p.inner;
  const long zB = (long)(z1 >> p.zBshift);
  const bf16* A = p.A + (long)z0 * p.sA0 + (long)z1 * p.sA1;
  const bf16* Bp = p.B + (long)z0 * p.sB0 + zB * p.sB1;
  const int m0 = blockIdx.x * BM, n0 = blockIdx.y * BN;
  const int wave = tid >> 6, lane = tid & 63;
  const int wrow = wave / WN, wcol = wave % WN;
  const int fr = lane & 15, quad = lane >> 4;
  const int swz = (quad ^ ((fr >> 1) & 3)) * 8;
  ffrag acc[TI][TJ] = {};
  constexpr int CH_A = BM * 4;
  constexpr int NIT = (BM + BN) * 4 / 256;
  for (int k0 = 0; k0 < p.K; k0 += 32) {
    const bf16* Asrc = A;
    int kc = k0;
    if constexpr (SPLIT) {
      if (k0 >= p.kSplit) { Asrc = p.A2; kc = k0 - p.kSplit; }
    }
#pragma unroll
    for (int it = 0; it < NIT; ++it) {
      int idx = it * 256 + tid;
      const bf16* g;
      if (idx < CH_A) {
        int r = idx >> 2, c = (idx & 3) ^ ((idx >> 3) & 3);
        g = Asrc + (long)(m0 + r) * p.lda + kc + c * 8;
      } else {
        int j = idx - CH_A;
        int r = j >> 2, c = (j & 3) ^ ((j >> 3) & 3);
        g = Bp + (long)(n0 + r) * p.ldb + k0 + c * 8;
      }
      __builtin_amdgcn_global_load_lds(
          (const __attribute__((address_space(1))) void*)g,
          (__attribute__((address_space(3))) void*)(smem + idx * 8), 16, 0, 0);
    }
    __syncthreads();
    bfrag af[TI], bfb[TJ];
#pragma unroll
    for (int t = 0; t < TI; ++t)
      af[t] = *(const bfrag*)(smem + ((wrow * (TI * 16) + t * 16 + fr) * 32 + swz));
#pragma unroll
    for (int t = 0; t < TJ; ++t)
      bfb[t] = *(const bfrag*)(smem + (BM * 32 + (wcol * (TJ * 16) + t * 16 + fr) * 32 + swz));
#pragma unroll
    for (int ti = 0; ti < TI; ++ti)
#pragma unroll
      for (int tj = 0; tj < TJ; ++tj)
        acc[ti][tj] = __builtin_amdgcn_mfma_f32_16x16x32_bf16(af[ti], bfb[tj], acc[ti][tj], 0, 0, 0);
    __syncthreads();
  }
  const int mbase = m0 + wrow * (TI * 16), nbase = n0 + wcol * (TJ * 16);
  void* Cb = p.C;
  long zc = (long)z0 * p.sC0 + (long)z1 * p.sC1;
  if (z == p.c2z) { Cb = p.C2; zc = 0; }
  const long zb = (long)z0 * p.sb0 + zB * p.sb1;
#pragma unroll
  for (int ti = 0; ti < TI; ++ti) {
#pragma unroll
    for (int tj = 0; tj < TJ; ++tj) {
#pragma unroll
      for (int r = 0; r < 4; ++r) {
        int m = mbase + ti * 16 + quad * 4 + r;
        int n = nbase + tj * 16 + fr;
        float v = acc[ti][tj][r] * p.scale;
        if (p.bias) v += p.bias[zb + n];
        long ci = zc + (long)m * p.ldc + n;
        if (p.mode == 0) ((bf16*)Cb)[ci] = __float2bfloat16(v);
        else if (p.mode == 1) ((float*)Cb)[ci] = v;
        else if (p.mode == 3) ((bf16*)Cb)[ci] = __float2bfloat16(gelu_f(v));
        else if (p.mode == 4) ((bf16*)Cb)[ci] = __float2bfloat16(v > 0.f ? v + 1.f : __expf(v));
        else ((bf16*)Cb)[ci] = __float2bfloat16(__expf(v - 16.f));
      }
    }
  }
}

// cfg 0: 128x128 | 1: 128x64 | 2: 64x64 | 3: 64x64 split-A
static void launch_gemm(hipStream_t st, int cfg, int M, int N, int batch, const GemmP& g) {
  dim3 bs(256);
  if (cfg == 0)      gemm_nt<128, 128, 2, 2, false><<<dim3(M / 128, N / 128, batch), bs, 0, st>>>(g);
  else if (cfg == 1) gemm_nt<128, 64, 2, 2, false><<<dim3(M / 128, N / 64, batch), bs, 0, st>>>(g);
  else if (cfg == 2) gemm_nt<64, 64, 2, 2, false><<<dim3(M / 64, N / 64, batch), bs, 0, st>>>(g);
  else               gemm_nt<64, 64, 2, 2, true><<<dim3(M / 64, N / 64, batch), bs, 0, st>>>(g);
}

// ---------------------------------------------------------------- GEMM 256-wide / BK=64
// 8-wave (2M x 4N) double-buffered schedule with counted vmcnt (T3+T4+T5).
// R1 addition: XCD-locality block swizzle. Default dispatch maps linear block
// id % 8 -> XCD; grid (gX,gY,gZ) with gX = M/BM has bx = lin%8, pinning A per
// XCD but streaming ALL of B through every XCD's 4 MB L2 (B 100% L2-miss ->
// every tile stalls on L3/HBM latency; R0 counters: MfmaUtil 20, VALU 11,
// FETCH 102 MB vs 28 MB unique). Remap: each XCD owns a 4-wide bx group x a
// contiguous (by,z) chunk, bx innermost, so each B panel's 4 consumers are
// temporally adjacent on one XCD -> B staging mostly L2-hit.
template <int BM2, int BN2>
__global__ __launch_bounds__(512)
void gemm_nt8(GemmP p) {
  constexpr int TI = BM2 / 32;              // m-frags per wave
  constexpr int TJ = BN2 / 64;              // n-frags per wave
  constexpr int BUFEL = (BM2 + BN2) * 64;   // elems per LDS buffer
  constexpr int NLA = BM2 / 64;             // A loads/thread/tile
  constexpr int NLB = BN2 / 64;             // B loads/thread/tile
  constexpr int NL = NLA + NLB;
  __shared__ __align__(16) bf16 smem[2 * BUFEL];
  const int tid = threadIdx.x;

  // ---- XCD-locality swizzle (bijective on (bx,by,z)) ----
  int bx = blockIdx.x, by = blockIdx.y, z = blockIdx.z;
  {
    const int gX = gridDim.x, gY = gridDim.y;
    const int byzTot = gY * gridDim.z;
    const int nbxg = gX >> 2;               // bx-groups of 4
    if (nbxg == 2 || nbxg == 4) {
      const int nbyzg = 8 / nbxg;           // (by,z)-groups
      if (byzTot % nbyzg == 0) {
        int lin = bx + gX * (by + gY * z);
        int xcd = lin & 7, q = lin >> 3;
        bx = (xcd % nbxg) * 4 + (q & 3);
        int byz = (xcd / nbxg) * (byzTot / nbyzg) + (q >> 2);
        by = byz % gY; z = byz / gY;
      }
    }
  }

  const int z0 = z % p.inner, z1 = z / p.inner;
  const long zB = (long)(z1 >> p.zBshift);
  const bf16* A = p.A + (long)z0 * p.sA0 + (long)z1 * p.sA1;
  const bf16* Bp = p.B + (long)z0 * p.sB0 + zB * p.sB1;
  const int m0 = bx * BM2, n0 = by * BN2;
  const int wave = tid >> 6, lane = tid & 63;
  const int wrow = wave >> 2, wcol = wave & 3;          // 2 x 4 waves
  const int fr = lane & 15, quad = lane >> 4;

  // per-thread staging sources (fixed row/chunk; +64 elems per K-tile)
  const bf16* gsrc[NL];
  int loff[NL];
#pragma unroll
  for (int i = 0; i < NLA; ++i) {
    int idx = i * 512 + tid;
    int r = idx >> 3, cs = idx & 7, c = cs ^ (r & 7);
    gsrc[i] = A + (long)(m0 + r) * p.lda + c * 8;
    loff[i] = idx * 8;
  }
#pragma unroll
  for (int i = 0; i < NLB; ++i) {
    int j = i * 512 + tid;
    int r = j >> 3, cs = j & 7, c = cs ^ (r & 7);
    gsrc[NLA + i] = Bp + (long)(n0 + r) * p.ldb + c * 8;
    loff[NLA + i] = BM2 * 64 + j * 8;
  }
  auto stage = [&](int buf) {
#pragma unroll
    for (int i = 0; i < NL; ++i) {
      __builtin_amdgcn_global_load_lds(
          (const __attribute__((address_space(1))) void*)gsrc[i],
          (__attribute__((address_space(3))) void*)(smem + buf * BUFEL + loff[i]),
          16, 0, 0);
      gsrc[i] += 64;
    }
  };

  // fragment read offsets: row r's chunk c sits at cs = c ^ (r&7); here
  // r & 7 == fr & 7 for every fragment row (ti*16, wrow*BM2/2 are 0 mod 8)
  const int cs0 = (quad ^ (fr & 7)) * 8;           // kk = 0
  const int cs1 = ((quad ^ (fr & 7)) ^ 4) * 8;     // kk = 1
  const int aBase = (wrow * (BM2 / 2) + fr) * 64;
  const int bBase = BM2 * 64 + (wcol * (TJ * 16) + fr) * 64;

  ffrag acc[TI][TJ] = {};
  const int NT = p.K >> 6;
  stage(0);
  stage(1);
  for (int kt = 0; kt < NT; ++kt) {
    const int cur = kt & 1;
    const bf16* sb = smem + cur * BUFEL;
    if (kt + 1 < NT) asm volatile("s_waitcnt vmcnt(%0)" ::"n"(NL) : "memory");
    else             asm volatile("s_waitcnt vmcnt(0)" ::: "memory");
    __builtin_amdgcn_s_barrier();      // all waves: tile kt fully resident
    asm volatile("" ::: "memory");
    bfrag b0[TJ], b1[TJ];
#pragma unroll
    for (int tj = 0; tj < TJ; ++tj) {
      b0[tj] = *(const bfrag*)(sb + bBase + tj * 1024 + cs0);
      b1[tj] = *(const bfrag*)(sb + bBase + tj * 1024 + cs1);
    }
#pragma unroll
    for (int ph = 0; ph < 4; ++ph) {
      __builtin_amdgcn_s_setprio(1);
#pragma unroll
      for (int t2 = 0; t2 < TI / 4; ++t2) {
        const int ti = ph * (TI / 4) + t2;
        bfrag a0 = *(const bfrag*)(sb + aBase + ti * 1024 + cs0);
        bfrag a1 = *(const bfrag*)(sb + aBase + ti * 1024 + cs1);
#pragma unroll
        for (int tj = 0; tj < TJ; ++tj) {
          acc[ti][tj] = __builtin_amdgcn_mfma_f32_16x16x32_bf16(a0, b0[tj], acc[ti][tj], 0, 0, 0);
          acc[ti][tj] = __builtin_amdgcn_mfma_f32_16x16x32_bf16(a1, b1[tj], acc[ti][tj], 0, 0, 0);
        }
      }
      __builtin_amdgcn_s_setprio(0);
    }
    asm volatile("" ::: "memory");
    __builtin_amdgcn_s_barrier();      // all waves done reading buf cur
    asm volatile("" ::: "memory");
    if (kt + 2 < NT) stage(cur);       // overwrite buf cur with tile kt+2
  }

  const int mbase = m0 + wrow * (BM2 / 2), nbase = n0 + wcol * (TJ * 16);
  void* Cb = p.C;
  long zc = (long)z0 * p.sC0 + (long)z1 * p.sC1;
  if (z == p.c2z) { Cb = p.C2; zc = 0; }
  const long zb = (long)z0 * p.sb0 + zB * p.sb1;
#pragma unroll
  for (int ti = 0; ti < TI; ++ti) {
#pragma unroll
    for (int tj = 0; tj < TJ; ++tj) {
#pragma unroll
      for (int r = 0; r < 4; ++r) {
        int m = mbase + ti * 16 + quad * 4 + r;
        int n = nbase + tj * 16 + fr;
        float v = acc[ti][tj][r] * p.scale;
        if (p.bias) v += p.bias[zb + n];
        ((bf16*)Cb)[zc + (long)m * p.ldc + n] = __float2bfloat16(v);
      }
    }
  }
}

// cfg 0: 256x256 | 1: 128x256 (for grids that underfill 256 CUs at 256x256)
static void launch_gemm8(hipStream_t st, int cfg, int M, int N, int batch, const GemmP& g) {
  if (cfg == 0)
    gemm_nt8<256, 256><<<dim3(M / 256, N / 256, batch), dim3(512), 0, st>>>(g);
  else
    gemm_nt8<128, 256><<<dim3(M / 128, N / 256, batch), dim3(512), 0, st>>>(g);
}

// ---------------------------------------------------------------- prep (all weight transposes)
// grid (32, 64, 42); src[R][C] f32 -> dst[C][R] bf16, demuxed on z
__global__ void prep_k(const float* w_qkvo, const float* sub_w1, const float* sub_w2,
                       const float* conv_pw, const float* fus_w, const float* r1_w1,
                       const float* r2_w1, const float* phi_w, const float* psi_w,
                       const float* phi_b, const float* psi_b,
                       bf16* wt, bf16* fuswt, bf16* r1w1t, bf16* r2w1t,
                       bf16* phiwt, bf16* psiwt, float* phipsib, bf16* vtp1) {
  int z = blockIdx.z;
  int bx = blockIdx.x, by = blockIdx.y;
  int tx = threadIdx.x & 31, ty = threadIdx.x >> 5;
  const float* src; bf16* dst; int R, C;
  if (z < 33) {
    if (by >= 32) return;
    src = z < 16 ? w_qkvo + (long)z * 1048576
        : z < 24 ? sub_w1 + (long)(z - 16) * 1048576
        : z < 32 ? sub_w2 + (long)(z - 24) * 1048576
                 : conv_pw;
    dst = wt + (long)z * 1048576; R = 1024; C = 1024;
  } else if (z == 33) {
    src = fus_w; dst = fuswt; R = 2048; C = 1024;
  } else if (z == 34) {
    if (bx >= 16 || by >= 32) return;
    src = r1_w1; dst = r1w1t; R = 1024; C = 512;
  } else if (z < 39) {
    if (bx >= 8 || by >= 32) return;
    src = r2_w1 + (long)(z - 35) * 262144; dst = r2w1t + (long)(z - 35) * 262144;
    R = 1024; C = 256;
  } else if (z < 41) {
    if (bx >= 8 || by >= 2) return;
    src = (z == 39) ? phi_w : psi_w; dst = (z == 39) ? phiwt : psiwt; R = 64; C = 256;
  } else {
    if (by == 0) {  // ones row (performer ksum trick): slice bx of VTP1
      for (int c = threadIdx.x; c < 1024; c += 256)
        vtp1[(long)bx * 131072 + 65536 + c] = __float2bfloat16(1.0f);
    } else if (by == 1 && bx == 0) {
      for (int i = threadIdx.x; i < 512; i += 256)
        phipsib[i] = i < 256 ? phi_b[i] : psi_b[i - 256];
    }
    return;
  }
  __shared__ float t[32][33];
  int c0 = bx * 32, r0 = by * 32;
#pragma unroll
  for (int i = 0; i < 32; i += 8)
    t[ty + i][tx] = src[(long)(r0 + ty + i) * C + c0 + tx];
  __syncthreads();
#pragma unroll
  for (int i = 0; i < 32; i += 8)
    dst[(long)(c0 + ty + i) * R + r0 + tx] = __float2bfloat16(t[tx][ty + i]);
}

// per-row: x->bf16, depthwise conv, token-importance dot — one x pass
__global__ void xprep_k(const float* x, const float* dw, const float* spw, const float* spb,
                        bf16* xb, bf16* t1, float* tokimp) {
  long row = blockIdx.x;                 // 2048 rows
  int s = (int)(row & 1023);
  int tid = threadIdx.x;
  const float* xr = x + row * 1024;
  float dot = 0.f;
#pragma unroll
  for (int i = 0; i < 4; ++i) {
    int d = tid + i * 256;
    float xv = xr[d];
    xb[row * 1024 + d] = __float2bfloat16(xv);
    float a = xv * dw[1024 + d];
    if (s > 0) a += xr[d - 1024] * dw[d];
    if (s < 1023) a += xr[d + 1024] * dw[2048 + d];
    t1[row * 1024 + d] = __float2bfloat16(a);
    dot += xv * spw[d];
  }
  float tot = bred_sum(dot);
  if (tid == 0) tokimp[row] = tot + spb[0];
}

// bf16 strided [z](R x C, row stride rs) -> bf16 out + z*ldz, out[c*R + r]
__global__ void transpose_bf16_k(const bf16* in, bf16* outp, int R, int C, int rs,
                                 int inner, int inner2, long is0, long is1, long is2,
                                 long ldz) {
  __shared__ bf16 t[32][33];
  int z = blockIdx.z;
  int z0 = z % inner; int zr = z / inner;
  int z1 = zr % inner2; int z2 = zr / inner2;
  long zo = (long)z0 * is0 + (long)z1 * is1 + (long)z2 * is2;
  int c0 = blockIdx.x * 32, r0 = blockIdx.y * 32;
  int tx = threadIdx.x & 31, ty = threadIdx.x >> 5;
#pragma unroll
  for (int i = 0; i < 32; i += 8)
    t[ty + i][tx] = in[zo + (long)(r0 + ty + i) * rs + c0 + tx];
  __syncthreads();
  long ob = (long)z * ldz;
#pragma unroll
  for (int i = 0; i < 32; i += 8)
    outp[ob + (long)(c0 + ty + i) * R + r0 + tx] = t[tx][ty + i];
}

// ones row 64 of 64 slices [128][1024] (attention denominator trick)
__global__ void vtones_k(bf16* vt) {
  int i = blockIdx.x * 256 + threadIdx.x;
  int z = i >> 10, c = i & 1023;
  vt[(long)z * 131072 + 65536 + c] = __float2bfloat16(1.0f);
}

// out[((b*1024+s)*1024) + h*64 + n] = in[(h+16b)*131072 + s*128 + n] / (in[..64]+eps)
__global__ void norm_k(const bf16* in, bf16* outp, float eps) {
  int r = blockIdx.x * 4 + (threadIdx.x >> 6);   // z*1024 + s
  int n = threadIdx.x & 63;
  int z = r >> 10, s = r & 1023;
  int h = z & 15, b = z >> 4;
  const bf16* ip = in + (long)r * 128;
  float den = __bfloat162float(ip[64]) + eps;
  float v = __bfloat162float(ip[n]);
  outp[((long)(b * 1024 + s) * 1024) + h * 64 + n] = __float2bfloat16(v / den);
}

// LN + act, single global read (register cache), N <= 1024
__global__ void ln_act_k(const void* in, const float* gamma, const float* beta,
                         bf16* outp, int N, int act, int rows_per_seg, int in_bf16) {
  long row = blockIdx.x;
  int tid = threadIdx.x;
  const bf16* ib = (const bf16*)in;
  const float* iff = (const float*)in;
  float vc[4];
  float ls = 0.f;
  int i = 0;
  for (int c = tid; c < N; c += 256, ++i) {
    float v = in_bf16 ? __bfloat162float(ib[row * N + c]) : iff[row * N + c];
    vc[i] = v; ls += v;
  }
  float mean = bred_sum(ls) / N;
  float lv = 0.f;
  i = 0;
  for (int c = tid; c < N; c += 256, ++i) { float d = vc[i] - mean; lv += d * d; }
  float rstd = rsqrtf(bred_sum(lv) / N + 1e-5f);
  long go = (row / rows_per_seg) * (long)N;
  const float* gp = gamma + go;
  const float* bp = beta + go;
  i = 0;
  for (int c = tid; c < N; c += 256, ++i) {
    float v = (vc[i] - mean) * rstd * gp[c] + bp[c];
    v = act ? gelu_f(v) : fmaxf(v, 0.f);
    outp[row * N + c] = __float2bfloat16(v);
  }
}

__global__ void topk_k(const float* timp, int* outp) {
  __shared__ float vals[1024];
  __shared__ float wv[4];
  __shared__ int wi[4];
  int b = blockIdx.x, tid = threadIdx.x;
  for (int c = tid; c < 1024; c += 256) vals[c] = timp[b * 1024 + c];
  __syncthreads();
  for (int t = 0; t < 10; ++t) {
    float bv = -3.0e38f; int bi = 1 << 30;
    for (int c = tid; c < 1024; c += 256) {
      float v = vals[c];
      if (v > bv || (v == bv && c < bi)) { bv = v; bi = c; }
    }
#pragma unroll
    for (int o = 32; o > 0; o >>= 1) {
      float ov = __shfl_xor(bv, o, 64); int oi = __shfl_xor(bi, o, 64);
      if (ov > bv || (ov == bv && oi < bi)) { bv = ov; bi = oi; }
    }
    int w = tid >> 6, l = tid & 63;
    if (l == 0) { wv[w] = bv; wi[w] = bi; }
    __syncthreads();
    if (tid == 0) {
      float fv = wv[0]; int fi = wi[0];
      for (int ww = 1; ww < 4; ++ww)
        if (wv[ww] > fv || (wv[ww] == fv && wi[ww] < fi)) { fv = wv[ww]; fi = wi[ww]; }
      outp[b * 16 + t] = fi;
      vals[fi] = -3.0e38f;
    }
    __syncthreads();
  }
}

// stage-1 V column sums: 512 blocks, partials [32][16][64]
__global__ void vsum_k(const bf16* v, float* vsump) {
  __shared__ float red[4][64];
  int zz = blockIdx.x;
  int z = zz >> 4, slab = zz & 15;
  int b = z >> 4, h = z & 15;
  const bf16* vp = v + (long)b * 1048576 + h * 64;
  int d = threadIdx.x & 63, sg = threadIdx.x >> 6;
  float s = 0.f;
#pragma unroll
  for (int i = 0; i < 16; ++i) {
    int srow = slab * 64 + sg * 16 + i;
    s += __bfloat162float(vp[(long)srow * 1024 + d]);
  }
  red[sg][d] = s;
  __syncthreads();
  if (sg == 0) vsump[(long)zz * 64 + d] = red[0][d] + red[1][d] + red[2][d] + red[3][d];
}

// expert-0 sparse attention, algebraically reduced
__global__ void sparse_attn_k(const bf16* q, const bf16* k, const bf16* v,
                              const float* vsump, const int* topidx, bf16* merged) {
  __shared__ float kt[10][64], vt[10][64], vs[64], vts[64];
  int z = blockIdx.y, b = z >> 4, h = z & 15;
  int tid = threadIdx.x;
  const int* tix = topidx + b * 16;
  for (int t = tid; t < 640; t += 256) {
    int tt = t >> 6, d = t & 63;
    long src = ((long)b * 1024 + tix[tt]) * 1024 + h * 64 + d;
    kt[tt][d] = __bfloat162float(k[src]);
    vt[tt][d] = __bfloat162float(v[src]);
  }
  if (tid < 64) {
    float s = 0.f;
#pragma unroll
    for (int p = 0; p < 16; ++p) s += vsump[((long)z * 16 + p) * 64 + tid];
    vs[tid] = s;
  }
  __syncthreads();
  if (tid < 64) {
    float s = 0.f;
#pragma unroll
    for (int t = 0; t < 10; ++t) s += vt[t][tid];
    vts[tid] = s;
  }
  __syncthreads();
  int wave = tid >> 6, lane = tid & 63;
  int sq = blockIdx.x * 4 + wave;
  long qi = ((long)b * 1024 + sq) * 1024 + h * 64 + lane;
  float qd = __bfloat162float(q[qi]);
  float sc[10];
#pragma unroll
  for (int t = 0; t < 10; ++t) sc[t] = wred_sum(qd * kt[t][lane]) * 0.125f;
  float m = 0.f;
#pragma unroll
  for (int t = 0; t < 10; ++t) m = fmaxf(m, sc[t]);
  float e[10], se = 0.f;
#pragma unroll
  for (int t = 0; t < 10; ++t) { e[t] = __expf(sc[t] - m); se += e[t]; }
  float em = __expf(-m);
  float Z = 1014.f * em + se;
  float o = em * (vs[lane] - vts[lane]);
#pragma unroll
  for (int t = 0; t < 10; ++t) o += e[t] * vt[t][lane];
  merged[qi] = __float2bfloat16(o / Z);
}

__global__ void router1_k(const bf16* h1, const float* w, const float* bias, float* outp) {
  int row = blockIdx.x * 4 + (threadIdx.x >> 6);
  int l = threadIdx.x & 63;
  const bf16* hp = h1 + (long)row * 512;
  float a0 = 0, a1 = 0, a2 = 0, a3 = 0;
  for (int c = l; c < 512; c += 64) {
    float hv = __bfloat162float(hp[c]);
    const float* wp = w + c * 4;
    a0 += hv * wp[0]; a1 += hv * wp[1]; a2 += hv * wp[2]; a3 += hv * wp[3];
  }
  a0 = wred_sum(a0); a1 = wred_sum(a1); a2 = wred_sum(a2); a3 = wred_sum(a3);
  a0 += bias[0]; a1 += bias[1]; a2 += bias[2]; a3 += bias[3];
  float m = fmaxf(fmaxf(a0, a1), fmaxf(a2, a3));
  float e0 = __expf(a0 - m), e1 = __expf(a1 - m), e2 = __expf(a2 - m), e3 = __expf(a3 - m);
  float inv = 1.f / (e0 + e1 + e2 + e3);
  if (l == 0) {
    float* op = outp + (long)row * 4;
    op[0] = e0 * inv; op[1] = e1 * inv; op[2] = e2 * inv; op[3] = e3 * inv;
  }
}

__global__ void router2_k(const bf16* h2, const float* w, const float* bias, float* outp,
                          int rows_per_seg) {
  int row = blockIdx.x * 4 + (threadIdx.x >> 6);
  int l = threadIdx.x & 63;
  int seg = row / rows_per_seg;
  const float* wp = w + (long)seg * 512;
  const float* bp = bias + (long)seg * 2;
  const bf16* hp = h2 + (long)row * 256;
  float a0 = 0, a1 = 0;
  for (int c = l; c < 256; c += 64) {
    float hv = __bfloat162float(hp[c]);
    a0 += hv * wp[c * 2]; a1 += hv * wp[c * 2 + 1];
  }
  a0 = wred_sum(a0); a1 = wred_sum(a1);
  a0 += bp[0]; a1 += bp[1];
  float m = fmaxf(a0, a1);
  float e0 = __expf(a0 - m), e1 = __expf(a1 - m);
  float inv = 1.f / (e0 + e1);
  if (l == 0) { outp[(long)row * 2] = e0 * inv; outp[(long)row * 2 + 1] = e1 * inv; }
}

// final: out[m,n] = sum_z p1[m][z/2] * p2[z/2][m][z&1] * part[z][m][n]
__global__ void combine_k(const bf16* part, const float* p1, const float* p2, float* outp) {
  long i = (long)blockIdx.x * 256 + threadIdx.x;
  long m = i >> 10;
  float acc = 0.f;
#pragma unroll
  for (int zz = 0; zz < 8; ++zz) {
    int e = zz >> 1, j = zz & 1;
    float w = p1[m * 4 + e] * p2[(long)e * 4096 + m * 2 + j];
    acc += w * __bfloat162float(part[(long)zz * 2097152 + i]);
  }
  outp[i] = acc;
}

// ---------------------------------------------------------------- host
extern "C" void kernel_launch(void* const* d_in, const int* in_sizes, int n_in,
                              void* d_out, int out_size, void* d_ws, size_t ws_size,
                              hipStream_t stream) {
  const float* x = (const float*)d_in[0];
  const float* w_qkvo = (const float*)d_in[1];
  const float* b_qkvo = (const float*)d_in[2];
  const float* sp_w = (const float*)d_in[3];
  const float* sp_b = (const float*)d_in[4];
  const float* phi_w = (const float*)d_in[5];
  const float* phi_b = (const float*)d_in[6];
  const float* psi_w = (const float*)d_in[7];
  const float* psi_b = (const float*)d_in[8];
  const float* conv_dw = (const float*)d_in[9];
  const float* conv_pw = (const float*)d_in[10];
  const float* fus_w = (const float*)d_in[11];
  const float* fus_b = (const float*)d_in[12];
  const float* sub_w1 = (const float*)d_in[13];
  const float* sub_b1 = (const float*)d_in[14];
  const float* sub_g = (const float*)d_in[15];
  const float* sub_be = (const float*)d_in[16];
  const float* sub_w2 = (const float*)d_in[17];
  const float* sub_b2 = (const float*)d_in[18];
  const float* r1_w1 = (const float*)d_in[19];
  const float* r1_b1 = (const float*)d_in[20];
  const float* r1_g = (const float*)d_in[21];
  const float* r1_be = (const float*)d_in[22];
  const float* r1_w2 = (const float*)d_in[23];
  const float* r1_b2 = (const float*)d_in[24];
  const float* r2_w1 = (const float*)d_in[25];
  const float* r2_b1 = (const float*)d_in[26];
  const float* r2_g = (const float*)d_in[27];
  const float* r2_be = (const float*)d_in[28];
  const float* r2_w2 = (const float*)d_in[29];
  const float* r2_b2 = (const float*)d_in[30];
  (void)in_sizes; (void)n_in; (void)ws_size; (void)out_size;

  char* ws = (char*)d_ws;
  size_t off = 0;
  auto take = [&](size_t bytes) { void* p = ws + off; off += (bytes + 255) & ~(size_t)255; return p; };

  const long EL2M = 2097152;  // 2048*1024
  const long EL1M = 1048576;  // 1024*1024

  bf16* XB      = (bf16*)take((size_t)EL2M * 2);
  bf16* WQKVOT  = (bf16*)take((size_t)16 * EL1M * 2);
  bf16* SUBW1T  = (bf16*)take((size_t)8 * EL1M * 2);
  bf16* SUBW2T  = (bf16*)take((size_t)8 * EL1M * 2);
  bf16* CONVPWT = (bf16*)take((size_t)EL1M * 2);
  bf16* FUSWT   = (bf16*)take((size_t)EL2M * 2);
  bf16* R1W1T   = (bf16*)take((size_t)512 * 1024 * 2);
  bf16* R2W1T   = (bf16*)take((size_t)4 * 256 * 1024 * 2);
  bf16* PHIWT   = (bf16*)take((size_t)16384 * 2);
  bf16* PSIWT   = (bf16*)take((size_t)16384 * 2);
  float* PHIPSIB = (float*)take((size_t)512 * 4);
  bf16* QKVB    = (bf16*)take((size_t)12 * EL2M * 2);  // + MERGED4 adjacent -> sub arena
  bf16* MERGED4 = (bf16*)take((size_t)4 * EL2M * 2);
  bf16* VTP1    = (bf16*)take((size_t)32 * 128 * 1024 * 2);  // also performer TNUM
  bf16* EO      = (bf16*)take((size_t)4 * EL2M * 2);
  bf16* T1      = (bf16*)take((size_t)EL2M * 2);       // survives SC phase
  bf16* ARENA   = (bf16*)take((size_t)64 * 1024 * 1024);
  float* PROBS1 = (float*)take((size_t)2048 * 4 * 4);
  float* PROBS2 = (float*)take((size_t)4 * 2048 * 2 * 4);
  float* TOKIMP = (float*)take((size_t)2048 * 4);
  int*   TOPIDX = (int*)take((size_t)2 * 16 * 4);
  float* VSUMP  = (float*)take((size_t)32 * 16 * 64 * 4);

  // ARENA phase 1 (performer):
  bf16* QPHI  = ARENA;                       // [32][1024][256]
  bf16* KPSI  = ARENA + 8388608;             // [32][1024][256]
  bf16* KPSIT = ARENA + 16777216;            // [32][256][1024]
  bf16* KVTX  = ARENA + 25165824;            // [32][128][256] (row64 = ksum)
  // ARENA phase 2 (attention): SC = full 64 MB
  bf16* SC = ARENA;                          // [32][1024][1024]
  // ARENA phase 3 (late, after SC dead):
  bf16* SUB2F = ARENA;                       // [8][2048][1024] bf16 partials
  float* F32TMP = (float*)(ARENA + 16777216);  // 8 MB
  bf16* H1 = ARENA + 20971520;               // [2048][512]
  bf16* H2 = ARENA + 22020096;               // [4*2048][256]
  bf16* AO = ARENA + 24117248;               // [2048][1024]
  bf16* XC = ARENA + 26214400;               // [2048][1024]
  // QKVB slice reuse (dead after sparse/performer phases):
  bf16* TNUM23 = QKVB;                       // slices 0-1: [32][1024][128] PV numerator+den
  bf16* VT23   = QKVB + 2 * EL2M;            // slices 2-5: [64][128][1024] V^T (+ones row 64)
  // sub arena (aliases QKVB+MERGED4, dead by then):
  bf16* SUB1A = QKVB;                        // [8][2048][1024]
  bf16* SUB1B = QKVB + 16777216;             // [8][2048][1024]

  // ---- phase 0: weights + x prep ----
  prep_k<<<dim3(32, 64, 42), 256, 0, stream>>>(w_qkvo, sub_w1, sub_w2, conv_pw, fus_w,
                                               r1_w1, r2_w1, phi_w, psi_w, phi_b, psi_b,
                                               WQKVOT, FUSWT, R1W1T, R2W1T,
                                               PHIWT, PSIWT, PHIPSIB, VTP1);
  xprep_k<<<2048, 256, 0, stream>>>(x, conv_dw, sp_w, sp_b, XB, T1, TOKIMP);

  // ---- QKV for all experts, one batch-12 GEMM (256x256 8-wave pipeline) ----
  {
    GemmP g = gp0();
    g.A = XB; g.lda = 1024;
    g.B = WQKVOT; g.ldb = 1024; g.sB0 = EL1M; g.sB1 = 4 * EL1M;
    g.C = QKVB; g.ldc = 1024; g.sC0 = EL2M; g.sC1 = 3 * EL2M;
    g.bias = b_qkvo; g.sb0 = 1024; g.sb1 = 4096;
    g.K = 1024; g.inner = 3; g.mode = 0;
    launch_gemm8(stream, 0, 2048, 1024, 12, g);
  }

  // ---- expert 0: sparse attention ----
  topk_k<<<2, 256, 0, stream>>>(TOKIMP, TOPIDX);
  vsum_k<<<512, 256, 0, stream>>>(QKVB + 2 * EL2M, VSUMP);
  sparse_attn_k<<<dim3(256, 32), 256, 0, stream>>>(QKVB, QKVB + EL2M, QKVB + 2 * EL2M,
                                                   VSUMP, TOPIDX, MERGED4);

  // ---- expert 1: performer ----
  {  // phi(Q) and psi(K) in one batch-64 GEMM
    GemmP g = gp0();
    g.A = QKVB + 3 * EL2M; g.lda = 1024; g.sA0 = 64; g.sA1 = EL1M;
    g.B = PHIWT; g.ldb = 64; g.sB1 = 16384; g.zBshift = 1;
    g.C = QPHI; g.ldc = 256; g.sC0 = 262144; g.sC1 = 16 * 262144L;
    g.bias = PHIPSIB; g.sb1 = 256;
    g.K = 64; g.inner = 16; g.mode = 4;
    launch_gemm(stream, 2, 1024, 256, 64, g);
  }
  transpose_bf16_k<<<dim3(8, 32, 32), 256, 0, stream>>>(KPSI, KPSIT, 1024, 256, 256,
                                                        32, 1, 262144, 0, 0, 262144);
  transpose_bf16_k<<<dim3(2, 32, 32), 256, 0, stream>>>(QKVB + 5 * EL2M, VTP1, 1024, 64, 1024,
                                                        16, 2, 64, EL1M, 0, 131072);
  {  // KVTX[m,d] = sum_l VTP1[m,l]*KPSIT[d,l]; row 64 = ksum
    GemmP g = gp0();
    g.A = VTP1; g.lda = 1024; g.sA0 = 131072; g.sA1 = 16 * 131072L;
    g.B = KPSIT; g.ldb = 1024; g.sB0 = 262144; g.sB1 = 16 * 262144L;
    g.C = KVTX; g.ldc = 256; g.sC0 = 32768; g.sC1 = 16 * 32768L;
    g.K = 1024; g.inner = 16; g.mode = 0;
    launch_gemm(stream, 2, 128, 256, 32, g);
  }
  {  // num+den: N=128 against KVTX (col 64 = qphi.ksum) -> TNUM (aliases VTP1)
    GemmP g = gp0();
    g.A = QPHI; g.lda = 256; g.sA0 = 262144; g.sA1 = 16 * 262144L;
    g.B = KVTX; g.ldb = 256; g.sB0 = 32768; g.sB1 = 16 * 32768L;
    g.C = VTP1; g.ldc = 128; g.sC0 = 131072; g.sC1 = 16 * 131072L;
    g.K = 256; g.inner = 16; g.mode = 0;
    launch_gemm(stream, 2, 1024, 128, 32, g);
  }
  norm_k<<<8192, 256, 0, stream>>>(VTP1, MERGED4 + EL2M, 1e-8f);

  // ---- V^T (+ones row) for experts 2,3 into dead QKVB slices 2-5 ----
  transpose_bf16_k<<<dim3(2, 32, 64), 256, 0, stream>>>(QKVB + 8 * EL2M, VT23, 1024, 64, 1024,
                                                        16, 2, 64, EL1M, 3 * EL2M, 131072);
  vtones_k<<<256, 256, 0, stream>>>(VT23);

  // ---- experts 2 & 3: softmax attention (exp fused in scores, sum via ones row) ----
  for (int e = 2; e <= 3; ++e) {
    const bf16* q = QKVB + (size_t)(e * 3 + 0) * EL2M;
    const bf16* k = QKVB + (size_t)(e * 3 + 1) * EL2M;
    {  // SC = exp(q k^T * scale - 16)
      GemmP g = gp0();
      g.A = q; g.lda = 1024; g.sA0 = 64; g.sA1 = EL1M;
      g.B = k; g.ldb = 1024; g.sB0 = 64; g.sB1 = EL1M;
      g.C = SC; g.ldc = 1024; g.sC0 = EL1M; g.sC1 = 16 * EL1M;
      g.K = 64; g.inner = 16; g.scale = 0.125f; g.mode = 6;
      launch_gemm(stream, 0, 1024, 1024, 32, g);
    }
    {  // expSC @ [V^T; ones] -> numerator cols 0..63, denominator col 64
      GemmP g = gp0();
      g.A = SC; g.lda = 1024; g.sA0 = EL1M; g.sA1 = 16 * EL1M;
      g.B = VT23 + (size_t)(e - 2) * 32 * 131072; g.ldb = 1024; g.sB0 = 131072; g.sB1 = 16 * 131072L;
      g.C = TNUM23; g.ldc = 128; g.sC0 = 131072; g.sC1 = 16 * 131072L;
      g.K = 1024; g.inner = 16; g.mode = 0;
      launch_gemm(stream, 2, 1024, 128, 32, g);
    }
    norm_k<<<8192, 256, 0, stream>>>(TNUM23, MERGED4 + (size_t)e * EL2M, 0.f);
  }

  // ---- batch-4 output projection (z=3 -> AO), 128x256 pipeline (fills 256 CUs) ----
  {
    GemmP g = gp0();
    g.A = MERGED4; g.lda = 1024; g.sA1 = EL2M;
    g.B = WQKVOT + 3 * EL1M; g.ldb = 1024; g.sB1 = 4 * EL1M;
    g.C = EO; g.ldc = 1024; g.sC1 = EL2M;
    g.C2 = AO; g.c2z = 3;
    g.bias = b_qkvo + 3 * 1024; g.sb1 = 4096;
    g.K = 1024; g.mode = 0;
    launch_gemm8(stream, 1, 2048, 1024, 4, g);
  }

  // ---- conv branch + fusion ----
  {
    GemmP g = gp0();
    g.A = T1; g.lda = 1024;
    g.B = CONVPWT; g.ldb = 1024;
    g.C = XC; g.ldc = 1024;
    g.K = 1024; g.mode = 3;
    launch_gemm(stream, 2, 2048, 1024, 1, g);
  }
  {  // fusion: A = [AO | XC], K=2048 (SPLIT variant)
    GemmP g = gp0();
    g.A = AO; g.A2 = XC; g.kSplit = 1024; g.lda = 1024;
    g.B = FUSWT; g.ldb = 2048;
    g.C = EO + 3 * EL2M; g.ldc = 1024;
    g.bias = fus_b; g.K = 2048; g.mode = 0;
    launch_gemm(stream, 3, 2048, 1024, 1, g);
  }

  // ---- routers ----
  {
    GemmP g = gp0();
    g.A = XB; g.lda = 1024;
    g.B = R1W1T; g.ldb = 1024;
    g.C = F32TMP; g.ldc = 512;
    g.bias = r1_b1; g.K = 1024; g.mode = 1;
    launch_gemm(stream, 2, 2048, 512, 1, g);
  }
  ln_act_k<<<2048, 256, 0, stream>>>(F32TMP, r1_g, r1_be, H1, 512, 0, 2048, 0);
  router1_k<<<512, 256, 0, stream>>>(H1, r1_w2, r1_b2, PROBS1);
  {
    GemmP g = gp0();
    g.A = EO; g.lda = 1024; g.sA1 = EL2M;
    g.B = R2W1T; g.ldb = 1024; g.sB1 = 262144;
    g.C = F32TMP; g.ldc = 256; g.sC1 = 2048 * 256;
    g.bias = r2_b1; g.sb1 = 256; g.K = 1024; g.mode = 1;
    launch_gemm(stream, 2, 2048, 256, 4, g);
  }
  ln_act_k<<<8192, 256, 0, stream>>>(F32TMP, r2_g, r2_be, H2, 256, 0, 2048, 0);
  router2_k<<<2048, 256, 0, stream>>>(H2, r2_w2, r2_b2, PROBS2, 2048);

  // ---- sub-experts: batch-8 everything (256x256 pipeline) ----
  {  // sub1: z = j + 2*i
    GemmP g = gp0();
    g.A = EO; g.lda = 1024; g.sA1 = EL2M;
    g.B = SUBW1T; g.ldb = 1024; g.sB0 = EL1M; g.sB1 = 2 * EL1M;
    g.C = SUB1A; g.ldc = 1024; g.sC0 = EL2M; g.sC1 = 2 * EL2M;
    g.bias = sub_b1; g.sb0 = 1024; g.sb1 = 2048;
    g.K = 1024; g.inner = 2; g.mode = 0;
    launch_gemm8(stream, 0, 2048, 1024, 8, g);
  }
  ln_act_k<<<16384, 256, 0, stream>>>(SUB1A, sub_g, sub_be, SUB1B, 1024, 1, 2048, 1);
  {  // sub2 partials (bias folded)
    GemmP g = gp0();
    g.A = SUB1B; g.lda = 1024; g.sA1 = EL2M;
    g.B = SUBW2T; g.ldb = 1024; g.sB1 = EL1M;
    g.C = SUB2F; g.ldc = 1024; g.sC1 = EL2M;
    g.bias = sub_b2; g.sb1 = 1024;
    g.K = 1024; g.mode = 0;
    launch_gemm8(stream, 0, 2048, 1024, 8, g);
  }
  combine_k<<<8192, 256, 0, stream>>>(SUB2F, PROBS1, PROBS2, (float*)d_out);
}

// Round 3
// 899.659 us; speedup vs baseline: 1.1052x; 1.0151x over previous
//
#include <hip/hip_runtime.h>
#include <hip/hip_bf16.h>
#include <cstdint>

using bf16 = __hip_bfloat16;
typedef __attribute__((ext_vector_type(8))) short bfrag;   // 8 x bf16 (4 VGPRs)
typedef __attribute__((ext_vector_type(4))) float ffrag;   // 4 x f32 acc

#define DEV __device__ __forceinline__

DEV float wred_sum(float v) {
#pragma unroll
  for (int o = 32; o > 0; o >>= 1) v += __shfl_xor(v, o, 64);
  return v;
}
DEV float bred_sum(float v) {
  __shared__ float r[4];
  int w = threadIdx.x >> 6, l = threadIdx.x & 63;
  v = wred_sum(v);
  __syncthreads();
  if (l == 0) r[w] = v;
  __syncthreads();
  return r[0] + r[1] + r[2] + r[3];
}
DEV float gelu_f(float x) {  // jax.nn.gelu approximate=True
  float x3 = x * x * x;
  return 0.5f * x * (1.0f + tanhf(0.7978845608028654f * (x + 0.044715f * x3)));
}

// ---------------------------------------------------------------- GEMM (NT)
// C[m,n] = sum_k A[m,k] * B[n,k]
struct GemmP {
  const bf16* A; const bf16* A2; const bf16* B; void* C; void* C2;
  const float* bias;
  int K, lda, ldb, ldc, inner, mode, zBshift, c2z, kSplit;
  long sA0, sA1, sB0, sB1, sC0, sC1, sb0, sb1;
  float scale;
};
// modes: 0 bf16 | 1 f32 | 3 bf16 gelu | 4 bf16 elu+1 | 6 bf16 exp(v-16)
static GemmP gp0() {
  GemmP g;
  g.A = nullptr; g.A2 = nullptr; g.B = nullptr; g.C = nullptr; g.C2 = nullptr;
  g.bias = nullptr;
  g.K = 0; g.lda = 0; g.ldb = 0; g.ldc = 0; g.inner = 1; g.mode = 0;
  g.zBshift = 0; g.c2z = -1; g.kSplit = 1 << 30;
  g.sA0 = 0; g.sA1 = 0; g.sB0 = 0; g.sB1 = 0; g.sC0 = 0; g.sC1 = 0;
  g.sb0 = 0; g.sb1 = 0; g.scale = 1.f;
  return g;
}

// LDS bank-conflict swizzle (verified: SQ_LDS_BANK_CONFLICT -> 0):
// row r stores its four 16-B chunks permuted by c ^= (r>>1)&3; staging picks
// the matching global chunk per lane, fragment read applies the same XOR.
template <int BM, int BN, int WM, int WN, bool SPLIT>
__global__ __launch_bounds__(256)
void gemm_nt(GemmP p) {
  constexpr int TI = BM / (WM * 16), TJ = BN / (WN * 16);
  __shared__ bf16 smem[(BM + BN) * 32];
  const int tid = threadIdx.x;
  const int z = blockIdx.z;
  const int z0 = z % p.inner, z1 = z / p.inner;
  const long zB = (long)(z1 >> p.zBshift);
  const bf16* A = p.A + (long)z0 * p.sA0 + (long)z1 * p.sA1;
  const bf16* Bp = p.B + (long)z0 * p.sB0 + zB * p.sB1;
  const int m0 = blockIdx.x * BM, n0 = blockIdx.y * BN;
  const int wave = tid >> 6, lane = tid & 63;
  const int wrow = wave / WN, wcol = wave % WN;
  const int fr = lane & 15, quad = lane >> 4;
  const int swz = (quad ^ ((fr >> 1) & 3)) * 8;
  ffrag acc[TI][TJ] = {};
  constexpr int CH_A = BM * 4;
  constexpr int NIT = (BM + BN) * 4 / 256;
  for (int k0 = 0; k0 < p.K; k0 += 32) {
    const bf16* Asrc = A;
    int kc = k0;
    if constexpr (SPLIT) {
      if (k0 >= p.kSplit) { Asrc = p.A2; kc = k0 - p.kSplit; }
    }
#pragma unroll
    for (int it = 0; it < NIT; ++it) {
      int idx = it * 256 + tid;
      const bf16* g;
      if (idx < CH_A) {
        int r = idx >> 2, c = (idx & 3) ^ ((idx >> 3) & 3);
        g = Asrc + (long)(m0 + r) * p.lda + kc + c * 8;
      } else {
        int j = idx - CH_A;
        int r = j >> 2, c = (j & 3) ^ ((j >> 3) & 3);
        g = Bp + (long)(n0 + r) * p.ldb + k0 + c * 8;
      }
      __builtin_amdgcn_global_load_lds(
          (const __attribute__((address_space(1))) void*)g,
          (__attribute__((address_space(3))) void*)(smem + idx * 8), 16, 0, 0);
    }
    __syncthreads();
    bfrag af[TI], bfb[TJ];
#pragma unroll
    for (int t = 0; t < TI; ++t)
      af[t] = *(const bfrag*)(smem + ((wrow * (TI * 16) + t * 16 + fr) * 32 + swz));
#pragma unroll
    for (int t = 0; t < TJ; ++t)
      bfb[t] = *(const bfrag*)(smem + (BM * 32 + (wcol * (TJ * 16) + t * 16 + fr) * 32 + swz));
#pragma unroll
    for (int ti = 0; ti < TI; ++ti)
#pragma unroll
      for (int tj = 0; tj < TJ; ++tj)
        acc[ti][tj] = __builtin_amdgcn_mfma_f32_16x16x32_bf16(af[ti], bfb[tj], acc[ti][tj], 0, 0, 0);
    __syncthreads();
  }
  const int mbase = m0 + wrow * (TI * 16), nbase = n0 + wcol * (TJ * 16);
  void* Cb = p.C;
  long zc = (long)z0 * p.sC0 + (long)z1 * p.sC1;
  if (z == p.c2z) { Cb = p.C2; zc = 0; }
  const long zb = (long)z0 * p.sb0 + zB * p.sb1;
#pragma unroll
  for (int ti = 0; ti < TI; ++ti) {
#pragma unroll
    for (int tj = 0; tj < TJ; ++tj) {
#pragma unroll
      for (int r = 0; r < 4; ++r) {
        int m = mbase + ti * 16 + quad * 4 + r;
        int n = nbase + tj * 16 + fr;
        float v = acc[ti][tj][r] * p.scale;
        if (p.bias) v += p.bias[zb + n];
        long ci = zc + (long)m * p.ldc + n;
        if (p.mode == 0) ((bf16*)Cb)[ci] = __float2bfloat16(v);
        else if (p.mode == 1) ((float*)Cb)[ci] = v;
        else if (p.mode == 3) ((bf16*)Cb)[ci] = __float2bfloat16(gelu_f(v));
        else if (p.mode == 4) ((bf16*)Cb)[ci] = __float2bfloat16(v > 0.f ? v + 1.f : __expf(v));
        else ((bf16*)Cb)[ci] = __float2bfloat16(__expf(v - 16.f));
      }
    }
  }
}

// cfg 0: 128x128 | 1: 128x64 | 2: 64x64 | 3: 64x64 split-A
static void launch_gemm(hipStream_t st, int cfg, int M, int N, int batch, const GemmP& g) {
  dim3 bs(256);
  if (cfg == 0)      gemm_nt<128, 128, 2, 2, false><<<dim3(M / 128, N / 128, batch), bs, 0, st>>>(g);
  else if (cfg == 1) gemm_nt<128, 64, 2, 2, false><<<dim3(M / 128, N / 64, batch), bs, 0, st>>>(g);
  else if (cfg == 2) gemm_nt<64, 64, 2, 2, false><<<dim3(M / 64, N / 64, batch), bs, 0, st>>>(g);
  else               gemm_nt<64, 64, 2, 2, true><<<dim3(M / 64, N / 64, batch), bs, 0, st>>>(g);
}

// ---------------------------------------------------------------- GEMM 8-wave / BK=64
// R3: full 8-phase schedule (T3+T4+T5, m201 template adapted):
// Per K-tile (slot t, buf c=t&1), 4 phases; phase p:
//   - ds_read this phase's fragments only (ph0: all 8 b-frags + a(ti 0..TIP-1);
//     ph p: a-frags for ti = p*TIP..)
//   - issue 2 staging loads:  ph0/ph1 -> A(t+1) into buf c^1 (fully dead since
//     slot t-1's end);  ph2/ph3 -> B(t+2) into buf c (B region of buf c is dead
//     after ph0's closing barrier: all b-frags are read in ph0 and each wave's
//     lgkmcnt(0) precedes its barrier#2)
//   - counted vmcnt ONLY at ph3 (vmcnt(NLB): oldest-8 = B(t+1)+A(t+1) retired,
//     B(t+2)'s NLB loads stay in flight -- never drains to 0 in steady state)
//   - barrier; lgkmcnt(0)+sched_barrier(0); setprio(1); 16 MFMA; setprio(0); barrier
// Mechanism (m218/m233): the per-phase grain lets ds_read latency of all 8
// waves overlap at the barrier, MFMA clusters give setprio something to
// arbitrate, and staging loads span phases instead of serializing at tile end.
// mode 0 (bf16 + bias + c2z) only. Requires K%64==0, NT>=3 (K>=192).
template <int BM2, int BN2>
__global__ __launch_bounds__(512)
void gemm_nt8(GemmP p) {
  constexpr int TI = BM2 / 32;              // m-frags per wave
  constexpr int TJ = BN2 / 64;              // n-frags per wave
  constexpr int TIP = TI / 4;               // m-frags per phase
  constexpr int BUFEL = (BM2 + BN2) * 64;   // elems per LDS buffer
  constexpr int NLA = BM2 / 64;             // A loads/thread/tile
  constexpr int NLB = BN2 / 64;             // B loads/thread/tile
  __shared__ __align__(16) bf16 smem[2 * BUFEL];
  const int tid = threadIdx.x;

  // ---- XCD-locality swizzle (bijective on (bx,by,z)) ----
  int bx = blockIdx.x, by = blockIdx.y, z = blockIdx.z;
  {
    const int gX = gridDim.x, gY = gridDim.y;
    const int byzTot = gY * gridDim.z;
    const int nbxg = gX >> 2;               // bx-groups of 4
    if (nbxg == 2 || nbxg == 4) {
      const int nbyzg = 8 / nbxg;           // (by,z)-groups
      if (byzTot % nbyzg == 0) {
        int lin = bx + gX * (by + gY * z);
        int xcd = lin & 7, q = lin >> 3;
        bx = (xcd % nbxg) * 4 + (q & 3);
        int byz = (xcd / nbxg) * (byzTot / nbyzg) + (q >> 2);
        by = byz % gY; z = byz / gY;
      }
    }
  }

  const int z0 = z % p.inner, z1 = z / p.inner;
  const long zB = (long)(z1 >> p.zBshift);
  const bf16* A = p.A + (long)z0 * p.sA0 + (long)z1 * p.sA1;
  const bf16* Bp = p.B + (long)z0 * p.sB0 + zB * p.sB1;
  const int m0 = bx * BM2, n0 = by * BN2;
  const int wave = tid >> 6, lane = tid & 63;
  const int wrow = wave >> 2, wcol = wave & 3;          // 2 x 4 waves
  const int fr = lane & 15, quad = lane >> 4;

  // per-thread staging sources (fixed row/chunk; +64 elems per issued tile)
  const bf16* gsrcA[NLA]; int loffA[NLA];
  const bf16* gsrcB[NLB]; int loffB[NLB];
#pragma unroll
  for (int i = 0; i < NLA; ++i) {
    int idx = i * 512 + tid;
    int r = idx >> 3, cs = idx & 7, c = cs ^ (r & 7);
    gsrcA[i] = A + (long)(m0 + r) * p.lda + c * 8;
    loffA[i] = idx * 8;
  }
#pragma unroll
  for (int j = 0; j < NLB; ++j) {
    int idx = j * 512 + tid;
    int r = idx >> 3, cs = idx & 7, c = cs ^ (r & 7);
    gsrcB[j] = Bp + (long)(n0 + r) * p.ldb + c * 8;
    loffB[j] = BM2 * 64 + idx * 8;
  }
  auto gload = [&](const bf16* g, bf16* l) {
    __builtin_amdgcn_global_load_lds(
        (const __attribute__((address_space(1))) void*)g,
        (__attribute__((address_space(3))) void*)l, 16, 0, 0);
  };

  // fragment read offsets: row r's chunk c sits at cs = c ^ (r&7); here
  // r & 7 == fr & 7 for every fragment row (ti*16, wrow*BM2/2 are 0 mod 8)
  const int cs0 = (quad ^ (fr & 7)) * 8;           // kk = 0
  const int cs1 = ((quad ^ (fr & 7)) ^ 4) * 8;     // kk = 1
  const int aBase = (wrow * (BM2 / 2) + fr) * 64;
  const int bBase = BM2 * 64 + (wcol * (TJ * 16) + fr) * 64;

  ffrag acc[TI][TJ] = {};
  const int NT = p.K >> 6;

  // prologue: A(0),B(0) -> buf0; B(1) -> buf1; wait tile 0 resident
#pragma unroll
  for (int i = 0; i < NLA; ++i) { gload(gsrcA[i], smem + loffA[i]); gsrcA[i] += 64; }
#pragma unroll
  for (int j = 0; j < NLB; ++j) { gload(gsrcB[j], smem + loffB[j]); gsrcB[j] += 64; }
#pragma unroll
  for (int j = 0; j < NLB; ++j) { gload(gsrcB[j], smem + BUFEL + loffB[j]); gsrcB[j] += 64; }
  asm volatile("s_waitcnt vmcnt(%0)" ::"n"(NLB) : "memory");
  __builtin_amdgcn_s_barrier();
  asm volatile("" ::: "memory");

  for (int kt = 0; kt < NT; ++kt) {
    const int cur = kt & 1;
    const bf16* sb = smem + cur * BUFEL;
    bf16* sCur = smem + cur * BUFEL;
    bf16* sOther = smem + (cur ^ 1) * BUFEL;
    bfrag bb0[TJ], bb1[TJ];
#pragma unroll
    for (int ph = 0; ph < 4; ++ph) {
      // --- ds_reads for this phase ---
      if (ph == 0) {
#pragma unroll
        for (int tj = 0; tj < TJ; ++tj) {
          bb0[tj] = *(const bfrag*)(sb + bBase + tj * 1024 + cs0);
          bb1[tj] = *(const bfrag*)(sb + bBase + tj * 1024 + cs1);
        }
      }
      bfrag a0[TIP], a1[TIP];
#pragma unroll
      for (int q = 0; q < TIP; ++q) {
        const int ti = ph * TIP + q;
        a0[q] = *(const bfrag*)(sb + aBase + ti * 1024 + cs0);
        a1[q] = *(const bfrag*)(sb + aBase + ti * 1024 + cs1);
      }
      // --- staging issues for this phase ---
      if (ph < 2) {
        if (kt + 1 < NT) {
#pragma unroll
          for (int i = 0; i < NLA / 2; ++i) {
            const int ii = ph * (NLA / 2) + i;
            gload(gsrcA[ii], sOther + loffA[ii]); gsrcA[ii] += 64;
          }
        }
      } else {
        if (kt + 2 < NT) {
#pragma unroll
          for (int j = 0; j < NLB / 2; ++j) {
            const int jj = (ph - 2) * (NLB / 2) + j;
            gload(gsrcB[jj], sCur + loffB[jj]); gsrcB[jj] += 64;
          }
        }
      }
      // --- counted vmcnt, once per tile, folded before ph3's barrier ---
      if (ph == 3 && kt + 1 < NT) {
        if (kt + 2 < NT) asm volatile("s_waitcnt vmcnt(%0)" ::"n"(NLB) : "memory");
        else             asm volatile("s_waitcnt vmcnt(0)" ::: "memory");
      }
      asm volatile("" ::: "memory");
      __builtin_amdgcn_s_barrier();
      asm volatile("s_waitcnt lgkmcnt(0)" ::: "memory");
      __builtin_amdgcn_sched_barrier(0);
      __builtin_amdgcn_s_setprio(1);
#pragma unroll
      for (int q = 0; q < TIP; ++q) {
        const int ti = ph * TIP + q;
#pragma unroll
        for (int tj = 0; tj < TJ; ++tj) {
          acc[ti][tj] = __builtin_amdgcn_mfma_f32_16x16x32_bf16(a0[q], bb0[tj], acc[ti][tj], 0, 0, 0);
          acc[ti][tj] = __builtin_amdgcn_mfma_f32_16x16x32_bf16(a1[q], bb1[tj], acc[ti][tj], 0, 0, 0);
        }
      }
      __builtin_amdgcn_s_setprio(0);
      asm volatile("" ::: "memory");
      __builtin_amdgcn_s_barrier();
      asm volatile("" ::: "memory");
    }
  }

  const int mbase = m0 + wrow * (BM2 / 2), nbase = n0 + wcol * (TJ * 16);
  void* Cb = p.C;
  long zc = (long)z0 * p.sC0 + (long)z1 * p.sC1;
  if (z == p.c2z) { Cb = p.C2; zc = 0; }
  const long zb = (long)z0 * p.sb0 + zB * p.sb1;
#pragma unroll
  for (int ti = 0; ti < TI; ++ti) {
#pragma unroll
    for (int tj = 0; tj < TJ; ++tj) {
#pragma unroll
      for (int r = 0; r < 4; ++r) {
        int m = mbase + ti * 16 + quad * 4 + r;
        int n = nbase + tj * 16 + fr;
        float v = acc[ti][tj][r] * p.scale;
        if (p.bias) v += p.bias[zb + n];
        ((bf16*)Cb)[zc + (long)m * p.ldc + n] = __float2bfloat16(v);
      }
    }
  }
}

// cfg 0: 256x256 | 1: 128x256 (grid balance: pick the one giving whole rounds)
static void launch_gemm8(hipStream_t st, int cfg, int M, int N, int batch, const GemmP& g) {
  if (cfg == 0)
    gemm_nt8<256, 256><<<dim3(M / 256, N / 256, batch), dim3(512), 0, st>>>(g);
  else
    gemm_nt8<128, 256><<<dim3(M / 128, N / 256, batch), dim3(512), 0, st>>>(g);
}

// ---------------------------------------------------------------- prep (all weight transposes)
// grid (32, 64, 42); src[R][C] f32 -> dst[C][R] bf16, demuxed on z
__global__ void prep_k(const float* w_qkvo, const float* sub_w1, const float* sub_w2,
                       const float* conv_pw, const float* fus_w, const float* r1_w1,
                       const float* r2_w1, const float* phi_w, const float* psi_w,
                       const float* phi_b, const float* psi_b,
                       bf16* wt, bf16* fuswt, bf16* r1w1t, bf16* r2w1t,
                       bf16* phiwt, bf16* psiwt, float* phipsib, bf16* vtp1) {
  int z = blockIdx.z;
  int bx = blockIdx.x, by = blockIdx.y;
  int tx = threadIdx.x & 31, ty = threadIdx.x >> 5;
  const float* src; bf16* dst; int R, C;
  if (z < 33) {
    if (by >= 32) return;
    src = z < 16 ? w_qkvo + (long)z * 1048576
        : z < 24 ? sub_w1 + (long)(z - 16) * 1048576
        : z < 32 ? sub_w2 + (long)(z - 24) * 1048576
                 : conv_pw;
    dst = wt + (long)z * 1048576; R = 1024; C = 1024;
  } else if (z == 33) {
    src = fus_w; dst = fuswt; R = 2048; C = 1024;
  } else if (z == 34) {
    if (bx >= 16 || by >= 32) return;
    src = r1_w1; dst = r1w1t; R = 1024; C = 512;
  } else if (z < 39) {
    if (bx >= 8 || by >= 32) return;
    src = r2_w1 + (long)(z - 35) * 262144; dst = r2w1t + (long)(z - 35) * 262144;
    R = 1024; C = 256;
  } else if (z < 41) {
    if (bx >= 8 || by >= 2) return;
    src = (z == 39) ? phi_w : psi_w; dst = (z == 39) ? phiwt : psiwt; R = 64; C = 256;
  } else {
    if (by == 0) {  // ones row (performer ksum trick): slice bx of VTP1
      for (int c = threadIdx.x; c < 1024; c += 256)
        vtp1[(long)bx * 131072 + 65536 + c] = __float2bfloat16(1.0f);
    } else if (by == 1 && bx == 0) {
      for (int i = threadIdx.x; i < 512; i += 256)
        phipsib[i] = i < 256 ? phi_b[i] : psi_b[i - 256];
    }
    return;
  }
  __shared__ float t[32][33];
  int c0 = bx * 32, r0 = by * 32;
#pragma unroll
  for (int i = 0; i < 32; i += 8)
    t[ty + i][tx] = src[(long)(r0 + ty + i) * C + c0 + tx];
  __syncthreads();
#pragma unroll
  for (int i = 0; i < 32; i += 8)
    dst[(long)(c0 + ty + i) * R + r0 + tx] = __float2bfloat16(t[tx][ty + i]);
}

// per-row: x->bf16, depthwise conv, token-importance dot — one x pass
__global__ void xprep_k(const float* x, const float* dw, const float* spw, const float* spb,
                        bf16* xb, bf16* t1, float* tokimp) {
  long row = blockIdx.x;                 // 2048 rows
  int s = (int)(row & 1023);
  int tid = threadIdx.x;
  const float* xr = x + row * 1024;
  float dot = 0.f;
#pragma unroll
  for (int i = 0; i < 4; ++i) {
    int d = tid + i * 256;
    float xv = xr[d];
    xb[row * 1024 + d] = __float2bfloat16(xv);
    float a = xv * dw[1024 + d];
    if (s > 0) a += xr[d - 1024] * dw[d];
    if (s < 1023) a += xr[d + 1024] * dw[2048 + d];
    t1[row * 1024 + d] = __float2bfloat16(a);
    dot += xv * spw[d];
  }
  float tot = bred_sum(dot);
  if (tid == 0) tokimp[row] = tot + spb[0];
}

// bf16 strided [z](R x C, row stride rs) -> bf16 out + z*ldz, out[c*R + r]
__global__ void transpose_bf16_k(const bf16* in, bf16* outp, int R, int C, int rs,
                                 int inner, int inner2, long is0, long is1, long is2,
                                 long ldz) {
  __shared__ bf16 t[32][33];
  int z = blockIdx.z;
  int z0 = z % inner; int zr = z / inner;
  int z1 = zr % inner2; int z2 = zr / inner2;
  long zo = (long)z0 * is0 + (long)z1 * is1 + (long)z2 * is2;
  int c0 = blockIdx.x * 32, r0 = blockIdx.y * 32;
  int tx = threadIdx.x & 31, ty = threadIdx.x >> 5;
#pragma unroll
  for (int i = 0; i < 32; i += 8)
    t[ty + i][tx] = in[zo + (long)(r0 + ty + i) * rs + c0 + tx];
  __syncthreads();
  long ob = (long)z * ldz;
#pragma unroll
  for (int i = 0; i < 32; i += 8)
    outp[ob + (long)(c0 + ty + i) * R + r0 + tx] = t[tx][ty + i];
}

// ones row 64 of 64 slices [128][1024] (attention denominator trick)
__global__ void vtones_k(bf16* vt) {
  int i = blockIdx.x * 256 + threadIdx.x;
  int z = i >> 10, c = i & 1023;
  vt[(long)z * 131072 + 65536 + c] = __float2bfloat16(1.0f);
}

// out[((b*1024+s)*1024) + h*64 + n] = in[(h+16b)*131072 + s*128 + n] / (in[..64]+eps)
__global__ void norm_k(const bf16* in, bf16* outp, float eps) {
  int r = blockIdx.x * 4 + (threadIdx.x >> 6);   // z*1024 + s
  int n = threadIdx.x & 63;
  int z = r >> 10, s = r & 1023;
  int h = z & 15, b = z >> 4;
  const bf16* ip = in + (long)r * 128;
  float den = __bfloat162float(ip[64]) + eps;
  float v = __bfloat162float(ip[n]);
  outp[((long)(b * 1024 + s) * 1024) + h * 64 + n] = __float2bfloat16(v / den);
}

// LN + act, single global read (register cache), N <= 1024
__global__ void ln_act_k(const void* in, const float* gamma, const float* beta,
                         bf16* outp, int N, int act, int rows_per_seg, int in_bf16) {
  long row = blockIdx.x;
  int tid = threadIdx.x;
  const bf16* ib = (const bf16*)in;
  const float* iff = (const float*)in;
  float vc[4];
  float ls = 0.f;
  int i = 0;
  for (int c = tid; c < N; c += 256, ++i) {
    float v = in_bf16 ? __bfloat162float(ib[row * N + c]) : iff[row * N + c];
    vc[i] = v; ls += v;
  }
  float mean = bred_sum(ls) / N;
  float lv = 0.f;
  i = 0;
  for (int c = tid; c < N; c += 256, ++i) { float d = vc[i] - mean; lv += d * d; }
  float rstd = rsqrtf(bred_sum(lv) / N + 1e-5f);
  long go = (row / rows_per_seg) * (long)N;
  const float* gp = gamma + go;
  const float* bp = beta + go;
  i = 0;
  for (int c = tid; c < N; c += 256, ++i) {
    float v = (vc[i] - mean) * rstd * gp[c] + bp[c];
    v = act ? gelu_f(v) : fmaxf(v, 0.f);
    outp[row * N + c] = __float2bfloat16(v);
  }
}

__global__ void topk_k(const float* timp, int* outp) {
  __shared__ float vals[1024];
  __shared__ float wv[4];
  __shared__ int wi[4];
  int b = blockIdx.x, tid = threadIdx.x;
  for (int c = tid; c < 1024; c += 256) vals[c] = timp[b * 1024 + c];
  __syncthreads();
  for (int t = 0; t < 10; ++t) {
    float bv = -3.0e38f; int bi = 1 << 30;
    for (int c = tid; c < 1024; c += 256) {
      float v = vals[c];
      if (v > bv || (v == bv && c < bi)) { bv = v; bi = c; }
    }
#pragma unroll
    for (int o = 32; o > 0; o >>= 1) {
      float ov = __shfl_xor(bv, o, 64); int oi = __shfl_xor(bi, o, 64);
      if (ov > bv || (ov == bv && oi < bi)) { bv = ov; bi = oi; }
    }
    int w = tid >> 6, l = tid & 63;
    if (l == 0) { wv[w] = bv; wi[w] = bi; }
    __syncthreads();
    if (tid == 0) {
      float fv = wv[0]; int fi = wi[0];
      for (int ww = 1; ww < 4; ++ww)
        if (wv[ww] > fv || (wv[ww] == fv && wi[ww] < fi)) { fv = wv[ww]; fi = wi[ww]; }
      outp[b * 16 + t] = fi;
      vals[fi] = -3.0e38f;
    }
    __syncthreads();
  }
}

// stage-1 V column sums: 512 blocks, partials [32][16][64]
__global__ void vsum_k(const bf16* v, float* vsump) {
  __shared__ float red[4][64];
  int zz = blockIdx.x;
  int z = zz >> 4, slab = zz & 15;
  int b = z >> 4, h = z & 15;
  const bf16* vp = v + (long)b * 1048576 + h * 64;
  int d = threadIdx.x & 63, sg = threadIdx.x >> 6;
  float s = 0.f;
#pragma unroll
  for (int i = 0; i < 16; ++i) {
    int srow = slab * 64 + sg * 16 + i;
    s += __bfloat162float(vp[(long)srow * 1024 + d]);
  }
  red[sg][d] = s;
  __syncthreads();
  if (sg == 0) vsump[(long)zz * 64 + d] = red[0][d] + red[1][d] + red[2][d] + red[3][d];
}

// expert-0 sparse attention, algebraically reduced
__global__ void sparse_attn_k(const bf16* q, const bf16* k, const bf16* v,
                              const float* vsump, const int* topidx, bf16* merged) {
  __shared__ float kt[10][64], vt[10][64], vs[64], vts[64];
  int z = blockIdx.y, b = z >> 4, h = z & 15;
  int tid = threadIdx.x;
  const int* tix = topidx + b * 16;
  for (int t = tid; t < 640; t += 256) {
    int tt = t >> 6, d = t & 63;
    long src = ((long)b * 1024 + tix[tt]) * 1024 + h * 64 + d;
    kt[tt][d] = __bfloat162float(k[src]);
    vt[tt][d] = __bfloat162float(v[src]);
  }
  if (tid < 64) {
    float s = 0.f;
#pragma unroll
    for (int p = 0; p < 16; ++p) s += vsump[((long)z * 16 + p) * 64 + tid];
    vs[tid] = s;
  }
  __syncthreads();
  if (tid < 64) {
    float s = 0.f;
#pragma unroll
    for (int t = 0; t < 10; ++t) s += vt[t][tid];
    vts[tid] = s;
  }
  __syncthreads();
  int wave = tid >> 6, lane = tid & 63;
  int sq = blockIdx.x * 4 + wave;
  long qi = ((long)b * 1024 + sq) * 1024 + h * 64 + lane;
  float qd = __bfloat162float(q[qi]);
  float sc[10];
#pragma unroll
  for (int t = 0; t < 10; ++t) sc[t] = wred_sum(qd * kt[t][lane]) * 0.125f;
  float m = 0.f;
#pragma unroll
  for (int t = 0; t < 10; ++t) m = fmaxf(m, sc[t]);
  float e[10], se = 0.f;
#pragma unroll
  for (int t = 0; t < 10; ++t) { e[t] = __expf(sc[t] - m); se += e[t]; }
  float em = __expf(-m);
  float Z = 1014.f * em + se;
  float o = em * (vs[lane] - vts[lane]);
#pragma unroll
  for (int t = 0; t < 10; ++t) o += e[t] * vt[t][lane];
  merged[qi] = __float2bfloat16(o / Z);
}

__global__ void router1_k(const bf16* h1, const float* w, const float* bias, float* outp) {
  int row = blockIdx.x * 4 + (threadIdx.x >> 6);
  int l = threadIdx.x & 63;
  const bf16* hp = h1 + (long)row * 512;
  float a0 = 0, a1 = 0, a2 = 0, a3 = 0;
  for (int c = l; c < 512; c += 64) {
    float hv = __bfloat162float(hp[c]);
    const float* wp = w + c * 4;
    a0 += hv * wp[0]; a1 += hv * wp[1]; a2 += hv * wp[2]; a3 += hv * wp[3];
  }
  a0 = wred_sum(a0); a1 = wred_sum(a1); a2 = wred_sum(a2); a3 = wred_sum(a3);
  a0 += bias[0]; a1 += bias[1]; a2 += bias[2]; a3 += bias[3];
  float m = fmaxf(fmaxf(a0, a1), fmaxf(a2, a3));
  float e0 = __expf(a0 - m), e1 = __expf(a1 - m), e2 = __expf(a2 - m), e3 = __expf(a3 - m);
  float inv = 1.f / (e0 + e1 + e2 + e3);
  if (l == 0) {
    float* op = outp + (long)row * 4;
    op[0] = e0 * inv; op[1] = e1 * inv; op[2] = e2 * inv; op[3] = e3 * inv;
  }
}

__global__ void router2_k(const bf16* h2, const float* w, const float* bias, float* outp,
                          int rows_per_seg) {
  int row = blockIdx.x * 4 + (threadIdx.x >> 6);
  int l = threadIdx.x & 63;
  int seg = row / rows_per_seg;
  const float* wp = w + (long)seg * 512;
  const float* bp = bias + (long)seg * 2;
  const bf16* hp = h2 + (long)row * 256;
  float a0 = 0, a1 = 0;
  for (int c = l; c < 256; c += 64) {
    float hv = __bfloat162float(hp[c]);
    a0 += hv * wp[c * 2]; a1 += hv * wp[c * 2 + 1];
  }
  a0 = wred_sum(a0); a1 = wred_sum(a1);
  a0 += bp[0]; a1 += bp[1];
  float m = fmaxf(a0, a1);
  float e0 = __expf(a0 - m), e1 = __expf(a1 - m);
  float inv = 1.f / (e0 + e1);
  if (l == 0) { outp[(long)row * 2] = e0 * inv; outp[(long)row * 2 + 1] = e1 * inv; }
}

// final: out[m,n] = sum_z p1[m][z/2] * p2[z/2][m][z&1] * part[z][m][n]
__global__ void combine_k(const bf16* part, const float* p1, const float* p2, float* outp) {
  long i = (long)blockIdx.x * 256 + threadIdx.x;
  long m = i >> 10;
  float acc = 0.f;
#pragma unroll
  for (int zz = 0; zz < 8; ++zz) {
    int e = zz >> 1, j = zz & 1;
    float w = p1[m * 4 + e] * p2[(long)e * 4096 + m * 2 + j];
    acc += w * __bfloat162float(part[(long)zz * 2097152 + i]);
  }
  outp[i] = acc;
}

// ---------------------------------------------------------------- host
extern "C" void kernel_launch(void* const* d_in, const int* in_sizes, int n_in,
                              void* d_out, int out_size, void* d_ws, size_t ws_size,
                              hipStream_t stream) {
  const float* x = (const float*)d_in[0];
  const float* w_qkvo = (const float*)d_in[1];
  const float* b_qkvo = (const float*)d_in[2];
  const float* sp_w = (const float*)d_in[3];
  const float* sp_b = (const float*)d_in[4];
  const float* phi_w = (const float*)d_in[5];
  const float* phi_b = (const float*)d_in[6];
  const float* psi_w = (const float*)d_in[7];
  const float* psi_b = (const float*)d_in[8];
  const float* conv_dw = (const float*)d_in[9];
  const float* conv_pw = (const float*)d_in[10];
  const float* fus_w = (const float*)d_in[11];
  const float* fus_b = (const float*)d_in[12];
  const float* sub_w1 = (const float*)d_in[13];
  const float* sub_b1 = (const float*)d_in[14];
  const float* sub_g = (const float*)d_in[15];
  const float* sub_be = (const float*)d_in[16];
  const float* sub_w2 = (const float*)d_in[17];
  const float* sub_b2 = (const float*)d_in[18];
  const float* r1_w1 = (const float*)d_in[19];
  const float* r1_b1 = (const float*)d_in[20];
  const float* r1_g = (const float*)d_in[21];
  const float* r1_be = (const float*)d_in[22];
  const float* r1_w2 = (const float*)d_in[23];
  const float* r1_b2 = (const float*)d_in[24];
  const float* r2_w1 = (const float*)d_in[25];
  const float* r2_b1 = (const float*)d_in[26];
  const float* r2_g = (const float*)d_in[27];
  const float* r2_be = (const float*)d_in[28];
  const float* r2_w2 = (const float*)d_in[29];
  const float* r2_b2 = (const float*)d_in[30];
  (void)in_sizes; (void)n_in; (void)ws_size; (void)out_size;

  char* ws = (char*)d_ws;
  size_t off = 0;
  auto take = [&](size_t bytes) { void* p = ws + off; off += (bytes + 255) & ~(size_t)255; return p; };

  const long EL2M = 2097152;  // 2048*1024
  const long EL1M = 1048576;  // 1024*1024

  bf16* XB      = (bf16*)take((size_t)EL2M * 2);
  bf16* WQKVOT  = (bf16*)take((size_t)16 * EL1M * 2);
  bf16* SUBW1T  = (bf16*)take((size_t)8 * EL1M * 2);
  bf16* SUBW2T  = (bf16*)take((size_t)8 * EL1M * 2);
  bf16* CONVPWT = (bf16*)take((size_t)EL1M * 2);
  bf16* FUSWT   = (bf16*)take((size_t)EL2M * 2);
  bf16* R1W1T   = (bf16*)take((size_t)512 * 1024 * 2);
  bf16* R2W1T   = (bf16*)take((size_t)4 * 256 * 1024 * 2);
  bf16* PHIWT   = (bf16*)take((size_t)16384 * 2);
  bf16* PSIWT   = (bf16*)take((size_t)16384 * 2);
  float* PHIPSIB = (float*)take((size_t)512 * 4);
  bf16* QKVB    = (bf16*)take((size_t)12 * EL2M * 2);  // + MERGED4 adjacent -> sub arena
  bf16* MERGED4 = (bf16*)take((size_t)4 * EL2M * 2);
  bf16* VTP1    = (bf16*)take((size_t)32 * 128 * 1024 * 2);  // also performer TNUM
  bf16* EO      = (bf16*)take((size_t)4 * EL2M * 2);
  bf16* T1      = (bf16*)take((size_t)EL2M * 2);       // survives SC phase
  bf16* ARENA   = (bf16*)take((size_t)64 * 1024 * 1024);
  float* PROBS1 = (float*)take((size_t)2048 * 4 * 4);
  float* PROBS2 = (float*)take((size_t)4 * 2048 * 2 * 4);
  float* TOKIMP = (float*)take((size_t)2048 * 4);
  int*   TOPIDX = (int*)take((size_t)2 * 16 * 4);
  float* VSUMP  = (float*)take((size_t)32 * 16 * 64 * 4);

  // ARENA phase 1 (performer):
  bf16* QPHI  = ARENA;                       // [32][1024][256]
  bf16* KPSI  = ARENA + 8388608;             // [32][1024][256]
  bf16* KPSIT = ARENA + 16777216;            // [32][256][1024]
  bf16* KVTX  = ARENA + 25165824;            // [32][128][256] (row64 = ksum)
  // ARENA phase 2 (attention): SC = full 64 MB
  bf16* SC = ARENA;                          // [32][1024][1024]
  // ARENA phase 3 (late, after SC dead):
  bf16* SUB2F = ARENA;                       // [8][2048][1024] bf16 partials
  float* F32TMP = (float*)(ARENA + 16777216);  // 8 MB
  bf16* H1 = ARENA + 20971520;               // [2048][512]
  bf16* H2 = ARENA + 22020096;               // [4*2048][256]
  bf16* AO = ARENA + 24117248;               // [2048][1024]
  bf16* XC = ARENA + 26214400;               // [2048][1024]
  // QKVB slice reuse (dead after sparse/performer phases):
  bf16* TNUM23 = QKVB;                       // slices 0-1: [32][1024][128] PV numerator+den
  bf16* VT23   = QKVB + 2 * EL2M;            // slices 2-5: [64][128][1024] V^T (+ones row 64)
  // sub arena (aliases QKVB+MERGED4, dead by then):
  bf16* SUB1A = QKVB;                        // [8][2048][1024]
  bf16* SUB1B = QKVB + 16777216;             // [8][2048][1024]

  // ---- phase 0: weights + x prep ----
  prep_k<<<dim3(32, 64, 42), 256, 0, stream>>>(w_qkvo, sub_w1, sub_w2, conv_pw, fus_w,
                                               r1_w1, r2_w1, phi_w, psi_w, phi_b, psi_b,
                                               WQKVOT, FUSWT, R1W1T, R2W1T,
                                               PHIWT, PSIWT, PHIPSIB, VTP1);
  xprep_k<<<2048, 256, 0, stream>>>(x, conv_dw, sp_w, sp_b, XB, T1, TOKIMP);

  // ---- QKV for all experts, one batch-12 GEMM (128x256, 768 blocks = 3.0 rounds) ----
  {
    GemmP g = gp0();
    g.A = XB; g.lda = 1024;
    g.B = WQKVOT; g.ldb = 1024; g.sB0 = EL1M; g.sB1 = 4 * EL1M;
    g.C = QKVB; g.ldc = 1024; g.sC0 = EL2M; g.sC1 = 3 * EL2M;
    g.bias = b_qkvo; g.sb0 = 1024; g.sb1 = 4096;
    g.K = 1024; g.inner = 3; g.mode = 0;
    launch_gemm8(stream, 1, 2048, 1024, 12, g);
  }

  // ---- expert 0: sparse attention ----
  topk_k<<<2, 256, 0, stream>>>(TOKIMP, TOPIDX);
  vsum_k<<<512, 256, 0, stream>>>(QKVB + 2 * EL2M, VSUMP);
  sparse_attn_k<<<dim3(256, 32), 256, 0, stream>>>(QKVB, QKVB + EL2M, QKVB + 2 * EL2M,
                                                   VSUMP, TOPIDX, MERGED4);

  // ---- expert 1: performer ----
  {  // phi(Q) and psi(K) in one batch-64 GEMM
    GemmP g = gp0();
    g.A = QKVB + 3 * EL2M; g.lda = 1024; g.sA0 = 64; g.sA1 = EL1M;
    g.B = PHIWT; g.ldb = 64; g.sB1 = 16384; g.zBshift = 1;
    g.C = QPHI; g.ldc = 256; g.sC0 = 262144; g.sC1 = 16 * 262144L;
    g.bias = PHIPSIB; g.sb1 = 256;
    g.K = 64; g.inner = 16; g.mode = 4;
    launch_gemm(stream, 2, 1024, 256, 64, g);
  }
  transpose_bf16_k<<<dim3(8, 32, 32), 256, 0, stream>>>(KPSI, KPSIT, 1024, 256, 256,
                                                        32, 1, 262144, 0, 0, 262144);
  transpose_bf16_k<<<dim3(2, 32, 32), 256, 0, stream>>>(QKVB + 5 * EL2M, VTP1, 1024, 64, 1024,
                                                        16, 2, 64, EL1M, 0, 131072);
  {  // KVTX[m,d] = sum_l VTP1[m,l]*KPSIT[d,l]; row 64 = ksum
    GemmP g = gp0();
    g.A = VTP1; g.lda = 1024; g.sA0 = 131072; g.sA1 = 16 * 131072L;
    g.B = KPSIT; g.ldb = 1024; g.sB0 = 262144; g.sB1 = 16 * 262144L;
    g.C = KVTX; g.ldc = 256; g.sC0 = 32768; g.sC1 = 16 * 32768L;
    g.K = 1024; g.inner = 16; g.mode = 0;
    launch_gemm(stream, 2, 128, 256, 32, g);
  }
  {  // num+den: N=128 against KVTX (col 64 = qphi.ksum) -> TNUM (aliases VTP1)
    GemmP g = gp0();
    g.A = QPHI; g.lda = 256; g.sA0 = 262144; g.sA1 = 16 * 262144L;
    g.B = KVTX; g.ldb = 256; g.sB0 = 32768; g.sB1 = 16 * 32768L;
    g.C = VTP1; g.ldc = 128; g.sC0 = 131072; g.sC1 = 16 * 131072L;
    g.K = 256; g.inner = 16; g.mode = 0;
    launch_gemm(stream, 2, 1024, 128, 32, g);
  }
  norm_k<<<8192, 256, 0, stream>>>(VTP1, MERGED4 + EL2M, 1e-8f);

  // ---- V^T (+ones row) for experts 2,3 into dead QKVB slices 2-5 ----
  transpose_bf16_k<<<dim3(2, 32, 64), 256, 0, stream>>>(QKVB + 8 * EL2M, VT23, 1024, 64, 1024,
                                                        16, 2, 64, EL1M, 3 * EL2M, 131072);
  vtones_k<<<256, 256, 0, stream>>>(VT23);

  // ---- experts 2 & 3: softmax attention (exp fused in scores, sum via ones row) ----
  for (int e = 2; e <= 3; ++e) {
    const bf16* q = QKVB + (size_t)(e * 3 + 0) * EL2M;
    const bf16* k = QKVB + (size_t)(e * 3 + 1) * EL2M;
    {  // SC = exp(q k^T * scale - 16)
      GemmP g = gp0();
      g.A = q; g.lda = 1024; g.sA0 = 64; g.sA1 = EL1M;
      g.B = k; g.ldb = 1024; g.sB0 = 64; g.sB1 = EL1M;
      g.C = SC; g.ldc = 1024; g.sC0 = EL1M; g.sC1 = 16 * EL1M;
      g.K = 64; g.inner = 16; g.scale = 0.125f; g.mode = 6;
      launch_gemm(stream, 0, 1024, 1024, 32, g);
    }
    {  // expSC @ [V^T; ones] -> numerator cols 0..63, denominator col 64
      GemmP g = gp0();
      g.A = SC; g.lda = 1024; g.sA0 = EL1M; g.sA1 = 16 * EL1M;
      g.B = VT23 + (size_t)(e - 2) * 32 * 131072; g.ldb = 1024; g.sB0 = 131072; g.sB1 = 16 * 131072L;
      g.C = TNUM23; g.ldc = 128; g.sC0 = 131072; g.sC1 = 16 * 131072L;
      g.K = 1024; g.inner = 16; g.mode = 0;
      launch_gemm(stream, 2, 1024, 128, 32, g);
    }
    norm_k<<<8192, 256, 0, stream>>>(TNUM23, MERGED4 + (size_t)e * EL2M, 0.f);
  }

  // ---- batch-4 output projection (z=3 -> AO), 128x256 (256 blocks = 1.0 round) ----
  {
    GemmP g = gp0();
    g.A = MERGED4; g.lda = 1024; g.sA1 = EL2M;
    g.B = WQKVOT + 3 * EL1M; g.ldb = 1024; g.sB1 = 4 * EL1M;
    g.C = EO; g.ldc = 1024; g.sC1 = EL2M;
    g.C2 = AO; g.c2z = 3;
    g.bias = b_qkvo + 3 * 1024; g.sb1 = 4096;
    g.K = 1024; g.mode = 0;
    launch_gemm8(stream, 1, 2048, 1024, 4, g);
  }

  // ---- conv branch + fusion ----
  {
    GemmP g = gp0();
    g.A = T1; g.lda = 1024;
    g.B = CONVPWT; g.ldb = 1024;
    g.C = XC; g.ldc = 1024;
    g.K = 1024; g.mode = 3;
    launch_gemm(stream, 2, 2048, 1024, 1, g);
  }
  {  // fusion: A = [AO | XC], K=2048 (SPLIT variant)
    GemmP g = gp0();
    g.A = AO; g.A2 = XC; g.kSplit = 1024; g.lda = 1024;
    g.B = FUSWT; g.ldb = 2048;
    g.C = EO + 3 * EL2M; g.ldc = 1024;
    g.bias = fus_b; g.K = 2048; g.mode = 0;
    launch_gemm(stream, 3, 2048, 1024, 1, g);
  }

  // ---- routers ----
  {
    GemmP g = gp0();
    g.A = XB; g.lda = 1024;
    g.B = R1W1T; g.ldb = 1024;
    g.C = F32TMP; g.ldc = 512;
    g.bias = r1_b1; g.K = 1024; g.mode = 1;
    launch_gemm(stream, 2, 2048, 512, 1, g);
  }
  ln_act_k<<<2048, 256, 0, stream>>>(F32TMP, r1_g, r1_be, H1, 512, 0, 2048, 0);
  router1_k<<<512, 256, 0, stream>>>(H1, r1_w2, r1_b2, PROBS1);
  {
    GemmP g = gp0();
    g.A = EO; g.lda = 1024; g.sA1 = EL2M;
    g.B = R2W1T; g.ldb = 1024; g.sB1 = 262144;
    g.C = F32TMP; g.ldc = 256; g.sC1 = 2048 * 256;
    g.bias = r2_b1; g.sb1 = 256; g.K = 1024; g.mode = 1;
    launch_gemm(stream, 2, 2048, 256, 4, g);
  }
  ln_act_k<<<8192, 256, 0, stream>>>(F32TMP, r2_g, r2_be, H2, 256, 0, 2048, 0);
  router2_k<<<2048, 256, 0, stream>>>(H2, r2_w2, r2_b2, PROBS2, 2048);

  // ---- sub-experts: batch-8 everything (256x256, 256 blocks = 1.0 round) ----
  {  // sub1: z = j + 2*i
    GemmP g = gp0();
    g.A = EO; g.lda = 1024; g.sA1 = EL2M;
    g.B = SUBW1T; g.ldb = 1024; g.sB0 = EL1M; g.sB1 = 2 * EL1M;
    g.C = SUB1A; g.ldc = 1024; g.sC0 = EL2M; g.sC1 = 2 * EL2M;
    g.bias = sub_b1; g.sb0 = 1024; g.sb1 = 2048;
    g.K = 1024; g.inner = 2; g.mode = 0;
    launch_gemm8(stream, 0, 2048, 1024, 8, g);
  }
  ln_act_k<<<16384, 256, 0, stream>>>(SUB1A, sub_g, sub_be, SUB1B, 1024, 1, 2048, 1);
  {  // sub2 partials (bias folded)
    GemmP g = gp0();
    g.A = SUB1B; g.lda = 1024; g.sA1 = EL2M;
    g.B = SUBW2T; g.ldb = 1024; g.sB1 = EL1M;
    g.C = SUB2F; g.ldc = 1024; g.sC1 = EL2M;
    g.bias = sub_b2; g.sb1 = 1024;
    g.K = 1024; g.mode = 0;
    launch_gemm8(stream, 0, 2048, 1024, 8, g);
  }
  combine_k<<<8192, 256, 0, stream>>>(SUB2F, PROBS1, PROBS2, (float*)d_out);
}

// Round 5
// 792.540 us; speedup vs baseline: 1.2546x; 1.1352x over previous
//
#include <hip/hip_runtime.h>
#include <hip/hip_bf16.h>
#include <cstdint>

using bf16 = __hip_bfloat16;
typedef __attribute__((ext_vector_type(8))) short bfrag;   // 8 x bf16 (4 VGPRs)
typedef __attribute__((ext_vector_type(4))) float ffrag;   // 4 x f32 acc

#define DEV __device__ __forceinline__

DEV float wred_sum(float v) {
#pragma unroll
  for (int o = 32; o > 0; o >>= 1) v += __shfl_xor(v, o, 64);
  return v;
}
DEV float bred_sum(float v) {
  __shared__ float r[4];
  int w = threadIdx.x >> 6, l = threadIdx.x & 63;
  v = wred_sum(v);
  __syncthreads();
  if (l == 0) r[w] = v;
  __syncthreads();
  return r[0] + r[1] + r[2] + r[3];
}
DEV float gelu_f(float x) {  // jax.nn.gelu approximate=True
  float x3 = x * x * x;
  return 0.5f * x * (1.0f + tanhf(0.7978845608028654f * (x + 0.044715f * x3)));
}
DEV uint32_t pack2bf(float lo, float hi) {  // explicit: lo -> bits[15:0]
  bf16 a = __float2bfloat16(lo), b = __float2bfloat16(hi);
  unsigned short ua, ub;
  __builtin_memcpy(&ua, &a, 2);
  __builtin_memcpy(&ub, &b, 2);
  return (uint32_t)ua | ((uint32_t)ub << 16);
}

// ---------------------------------------------------------------- GEMM (NT)
// C[m,n] = sum_k A[m,k] * B[n,k]
struct GemmP {
  const bf16* A; const bf16* A2; const bf16* B; void* C; void* C2;
  const float* bias;
  int K, lda, ldb, ldc, inner, mode, zBshift, c2z, kSplit;
  long sA0, sA1, sB0, sB1, sC0, sC1, sb0, sb1;
  float scale;
};
// modes: 0 bf16 | 1 f32 | 3 bf16 gelu | 4 bf16 elu+1 | 6 bf16 exp(v-16)
static GemmP gp0() {
  GemmP g;
  g.A = nullptr; g.A2 = nullptr; g.B = nullptr; g.C = nullptr; g.C2 = nullptr;
  g.bias = nullptr;
  g.K = 0; g.lda = 0; g.ldb = 0; g.ldc = 0; g.inner = 1; g.mode = 0;
  g.zBshift = 0; g.c2z = -1; g.kSplit = 1 << 30;
  g.sA0 = 0; g.sA1 = 0; g.sB0 = 0; g.sB1 = 0; g.sC0 = 0; g.sC1 = 0;
  g.sb0 = 0; g.sb1 = 0; g.scale = 1.f;
  return g;
}

// LDS bank-conflict swizzle (verified: SQ_LDS_BANK_CONFLICT -> 0):
// row r stores its four 16-B chunks permuted by c ^= (r>>1)&3; staging picks
// the matching global chunk per lane, fragment read applies the same XOR.
template <int BM, int BN, int WM, int WN, bool SPLIT>
__global__ __launch_bounds__(256)
void gemm_nt(GemmP p) {
  constexpr int TI = BM / (WM * 16), TJ = BN / (WN * 16);
  __shared__ bf16 smem[(BM + BN) * 32];
  const int tid = threadIdx.x;
  const int z = blockIdx.z;
  const int z0 = z % p.inner, z1 = z / p.inner;
  const long zB = (long)(z1 >> p.zBshift);
  const bf16* A = p.A + (long)z0 * p.sA0 + (long)z1 * p.sA1;
  const bf16* Bp = p.B + (long)z0 * p.sB0 + zB * p.sB1;
  const int m0 = blockIdx.x * BM, n0 = blockIdx.y * BN;
  const int wave = tid >> 6, lane = tid & 63;
  const int wrow = wave / WN, wcol = wave % WN;
  const int fr = lane & 15, quad = lane >> 4;
  const int swz = (quad ^ ((fr >> 1) & 3)) * 8;
  ffrag acc[TI][TJ] = {};
  constexpr int CH_A = BM * 4;
  constexpr int NIT = (BM + BN) * 4 / 256;
  for (int k0 = 0; k0 < p.K; k0 += 32) {
    const bf16* Asrc = A;
    int kc = k0;
    if constexpr (SPLIT) {
      if (k0 >= p.kSplit) { Asrc = p.A2; kc = k0 - p.kSplit; }
    }
#pragma unroll
    for (int it = 0; it < NIT; ++it) {
      int idx = it * 256 + tid;
      const bf16* g;
      if (idx < CH_A) {
        int r = idx >> 2, c = (idx & 3) ^ ((idx >> 3) & 3);
        g = Asrc + (long)(m0 + r) * p.lda + kc + c * 8;
      } else {
        int j = idx - CH_A;
        int r = j >> 2, c = (j & 3) ^ ((j >> 3) & 3);
        g = Bp + (long)(n0 + r) * p.ldb + k0 + c * 8;
      }
      __builtin_amdgcn_global_load_lds(
          (const __attribute__((address_space(1))) void*)g,
          (__attribute__((address_space(3))) void*)(smem + idx * 8), 16, 0, 0);
    }
    __syncthreads();
    bfrag af[TI], bfb[TJ];
#pragma unroll
    for (int t = 0; t < TI; ++t)
      af[t] = *(const bfrag*)(smem + ((wrow * (TI * 16) + t * 16 + fr) * 32 + swz));
#pragma unroll
    for (int t = 0; t < TJ; ++t)
      bfb[t] = *(const bfrag*)(smem + (BM * 32 + (wcol * (TJ * 16) + t * 16 + fr) * 32 + swz));
#pragma unroll
    for (int ti = 0; ti < TI; ++ti)
#pragma unroll
      for (int tj = 0; tj < TJ; ++tj)
        acc[ti][tj] = __builtin_amdgcn_mfma_f32_16x16x32_bf16(af[ti], bfb[tj], acc[ti][tj], 0, 0, 0);
    __syncthreads();
  }
  const int mbase = m0 + wrow * (TI * 16), nbase = n0 + wcol * (TJ * 16);
  void* Cb = p.C;
  long zc = (long)z0 * p.sC0 + (long)z1 * p.sC1;
  if (z == p.c2z) { Cb = p.C2; zc = 0; }
  const long zb = (long)z0 * p.sb0 + zB * p.sb1;
#pragma unroll
  for (int ti = 0; ti < TI; ++ti) {
#pragma unroll
    for (int tj = 0; tj < TJ; ++tj) {
#pragma unroll
      for (int r = 0; r < 4; ++r) {
        int m = mbase + ti * 16 + quad * 4 + r;
        int n = nbase + tj * 16 + fr;
        float v = acc[ti][tj][r] * p.scale;
        if (p.bias) v += p.bias[zb + n];
        long ci = zc + (long)m * p.ldc + n;
        if (p.mode == 0) ((bf16*)Cb)[ci] = __float2bfloat16(v);
        else if (p.mode == 1) ((float*)Cb)[ci] = v;
        else if (p.mode == 3) ((bf16*)Cb)[ci] = __float2bfloat16(gelu_f(v));
        else if (p.mode == 4) ((bf16*)Cb)[ci] = __float2bfloat16(v > 0.f ? v + 1.f : __expf(v));
        else ((bf16*)Cb)[ci] = __float2bfloat16(__expf(v - 16.f));
      }
    }
  }
}

// cfg 0: 128x128 | 1: 128x64 | 2: 64x64 | 3: 64x64 split-A
static void launch_gemm(hipStream_t st, int cfg, int M, int N, int batch, const GemmP& g) {
  dim3 bs(256);
  if (cfg == 0)      gemm_nt<128, 128, 2, 2, false><<<dim3(M / 128, N / 128, batch), bs, 0, st>>>(g);
  else if (cfg == 1) gemm_nt<128, 64, 2, 2, false><<<dim3(M / 128, N / 64, batch), bs, 0, st>>>(g);
  else if (cfg == 2) gemm_nt<64, 64, 2, 2, false><<<dim3(M / 64, N / 64, batch), bs, 0, st>>>(g);
  else               gemm_nt<64, 64, 2, 2, true><<<dim3(M / 64, N / 64, batch), bs, 0, st>>>(g);
}

// ---------------------------------------------------------------- GEMM 8-wave / BK=64
// 8-phase schedule (T3+T4+T5); see R3 notes. mode 0 only; K%64==0, K>=192.
template <int BM2, int BN2>
__global__ __launch_bounds__(512)
void gemm_nt8(GemmP p) {
  constexpr int TI = BM2 / 32;              // m-frags per wave
  constexpr int TJ = BN2 / 64;              // n-frags per wave
  constexpr int TIP = TI / 4;               // m-frags per phase
  constexpr int BUFEL = (BM2 + BN2) * 64;   // elems per LDS buffer
  constexpr int NLA = BM2 / 64;             // A loads/thread/tile
  constexpr int NLB = BN2 / 64;             // B loads/thread/tile
  __shared__ __align__(16) bf16 smem[2 * BUFEL];
  const int tid = threadIdx.x;

  // ---- XCD-locality swizzle (bijective on (bx,by,z)) ----
  int bx = blockIdx.x, by = blockIdx.y, z = blockIdx.z;
  {
    const int gX = gridDim.x, gY = gridDim.y;
    const int byzTot = gY * gridDim.z;
    const int nbxg = gX >> 2;               // bx-groups of 4
    if (nbxg == 2 || nbxg == 4) {
      const int nbyzg = 8 / nbxg;           // (by,z)-groups
      if (byzTot % nbyzg == 0) {
        int lin = bx + gX * (by + gY * z);
        int xcd = lin & 7, q = lin >> 3;
        bx = (xcd % nbxg) * 4 + (q & 3);
        int byz = (xcd / nbxg) * (byzTot / nbyzg) + (q >> 2);
        by = byz % gY; z = byz / gY;
      }
    }
  }

  const int z0 = z % p.inner, z1 = z / p.inner;
  const long zB = (long)(z1 >> p.zBshift);
  const bf16* A = p.A + (long)z0 * p.sA0 + (long)z1 * p.sA1;
  const bf16* Bp = p.B + (long)z0 * p.sB0 + zB * p.sB1;
  const int m0 = bx * BM2, n0 = by * BN2;
  const int wave = tid >> 6, lane = tid & 63;
  const int wrow = wave >> 2, wcol = wave & 3;          // 2 x 4 waves
  const int fr = lane & 15, quad = lane >> 4;

  // per-thread staging sources (fixed row/chunk; +64 elems per issued tile)
  const bf16* gsrcA[NLA]; int loffA[NLA];
  const bf16* gsrcB[NLB]; int loffB[NLB];
#pragma unroll
  for (int i = 0; i < NLA; ++i) {
    int idx = i * 512 + tid;
    int r = idx >> 3, cs = idx & 7, c = cs ^ (r & 7);
    gsrcA[i] = A + (long)(m0 + r) * p.lda + c * 8;
    loffA[i] = idx * 8;
  }
#pragma unroll
  for (int j = 0; j < NLB; ++j) {
    int idx = j * 512 + tid;
    int r = idx >> 3, cs = idx & 7, c = cs ^ (r & 7);
    gsrcB[j] = Bp + (long)(n0 + r) * p.ldb + c * 8;
    loffB[j] = BM2 * 64 + idx * 8;
  }
  auto gload = [&](const bf16* g, bf16* l) {
    __builtin_amdgcn_global_load_lds(
        (const __attribute__((address_space(1))) void*)g,
        (__attribute__((address_space(3))) void*)l, 16, 0, 0);
  };

  const int cs0 = (quad ^ (fr & 7)) * 8;           // kk = 0
  const int cs1 = ((quad ^ (fr & 7)) ^ 4) * 8;     // kk = 1
  const int aBase = (wrow * (BM2 / 2) + fr) * 64;
  const int bBase = BM2 * 64 + (wcol * (TJ * 16) + fr) * 64;

  ffrag acc[TI][TJ] = {};
  const int NT = p.K >> 6;

  // prologue: A(0),B(0) -> buf0; B(1) -> buf1; wait tile 0 resident
#pragma unroll
  for (int i = 0; i < NLA; ++i) { gload(gsrcA[i], smem + loffA[i]); gsrcA[i] += 64; }
#pragma unroll
  for (int j = 0; j < NLB; ++j) { gload(gsrcB[j], smem + loffB[j]); gsrcB[j] += 64; }
#pragma unroll
  for (int j = 0; j < NLB; ++j) { gload(gsrcB[j], smem + BUFEL + loffB[j]); gsrcB[j] += 64; }
  asm volatile("s_waitcnt vmcnt(%0)" ::"n"(NLB) : "memory");
  __builtin_amdgcn_s_barrier();
  asm volatile("" ::: "memory");

  for (int kt = 0; kt < NT; ++kt) {
    const int cur = kt & 1;
    const bf16* sb = smem + cur * BUFEL;
    bf16* sCur = smem + cur * BUFEL;
    bf16* sOther = smem + (cur ^ 1) * BUFEL;
    bfrag bb0[TJ], bb1[TJ];
#pragma unroll
    for (int ph = 0; ph < 4; ++ph) {
      if (ph == 0) {
#pragma unroll
        for (int tj = 0; tj < TJ; ++tj) {
          bb0[tj] = *(const bfrag*)(sb + bBase + tj * 1024 + cs0);
          bb1[tj] = *(const bfrag*)(sb + bBase + tj * 1024 + cs1);
        }
      }
      bfrag a0[TIP], a1[TIP];
#pragma unroll
      for (int q = 0; q < TIP; ++q) {
        const int ti = ph * TIP + q;
        a0[q] = *(const bfrag*)(sb + aBase + ti * 1024 + cs0);
        a1[q] = *(const bfrag*)(sb + aBase + ti * 1024 + cs1);
      }
      if (ph < 2) {
        if (kt + 1 < NT) {
#pragma unroll
          for (int i = 0; i < NLA / 2; ++i) {
            const int ii = ph * (NLA / 2) + i;
            gload(gsrcA[ii], sOther + loffA[ii]); gsrcA[ii] += 64;
          }
        }
      } else {
        if (kt + 2 < NT) {
#pragma unroll
          for (int j = 0; j < NLB / 2; ++j) {
            const int jj = (ph - 2) * (NLB / 2) + j;
            gload(gsrcB[jj], sCur + loffB[jj]); gsrcB[jj] += 64;
          }
        }
      }
      if (ph == 3 && kt + 1 < NT) {
        if (kt + 2 < NT) asm volatile("s_waitcnt vmcnt(%0)" ::"n"(NLB) : "memory");
        else             asm volatile("s_waitcnt vmcnt(0)" ::: "memory");
      }
      asm volatile("" ::: "memory");
      __builtin_amdgcn_s_barrier();
      asm volatile("s_waitcnt lgkmcnt(0)" ::: "memory");
      __builtin_amdgcn_sched_barrier(0);
      __builtin_amdgcn_s_setprio(1);
#pragma unroll
      for (int q = 0; q < TIP; ++q) {
        const int ti = ph * TIP + q;
#pragma unroll
        for (int tj = 0; tj < TJ; ++tj) {
          acc[ti][tj] = __builtin_amdgcn_mfma_f32_16x16x32_bf16(a0[q], bb0[tj], acc[ti][tj], 0, 0, 0);
          acc[ti][tj] = __builtin_amdgcn_mfma_f32_16x16x32_bf16(a1[q], bb1[tj], acc[ti][tj], 0, 0, 0);
        }
      }
      __builtin_amdgcn_s_setprio(0);
      asm volatile("" ::: "memory");
      __builtin_amdgcn_s_barrier();
      asm volatile("" ::: "memory");
    }
  }

  const int mbase = m0 + wrow * (BM2 / 2), nbase = n0 + wcol * (TJ * 16);
  void* Cb = p.C;
  long zc = (long)z0 * p.sC0 + (long)z1 * p.sC1;
  if (z == p.c2z) { Cb = p.C2; zc = 0; }
  const long zb = (long)z0 * p.sb0 + zB * p.sb1;
#pragma unroll
  for (int ti = 0; ti < TI; ++ti) {
#pragma unroll
    for (int tj = 0; tj < TJ; ++tj) {
#pragma unroll
      for (int r = 0; r < 4; ++r) {
        int m = mbase + ti * 16 + quad * 4 + r;
        int n = nbase + tj * 16 + fr;
        float v = acc[ti][tj][r] * p.scale;
        if (p.bias) v += p.bias[zb + n];
        ((bf16*)Cb)[zc + (long)m * p.ldc + n] = __float2bfloat16(v);
      }
    }
  }
}

// cfg 0: 256x256 | 1: 128x256
static void launch_gemm8(hipStream_t st, int cfg, int M, int N, int batch, const GemmP& g) {
  if (cfg == 0)
    gemm_nt8<256, 256><<<dim3(M / 256, N / 256, batch), dim3(512), 0, st>>>(g);
  else
    gemm_nt8<128, 256><<<dim3(M / 128, N / 256, batch), dim3(512), 0, st>>>(g);
}

// ---------------------------------------------------------------- fused attention (experts 2&3)
// R5: R4's fused kernel + two correctness fixes:
//  (a) FULL compiler memory fence + lgkmcnt(0) + sched_barrier(0) between the
//      P LDS stores and the PV LDS reads -- the store type (uint2) and read
//      type (short8) differ, so TBAA could legally reorder them (the only
//      compiler-visible LDS write->read pair in the program; everywhere else
//      the write side is the opaque global_load_lds builtin).
//  (b) bf16 packing via __float2bfloat16 + memcpy (no inline-asm cvt_pk whose
//      operand order was unverified).
__global__ __launch_bounds__(256)
void fused_attn_k(const bf16* qkvb, const bf16* vt23, bf16* out2, bf16* out3) {
  __shared__ __align__(16) bf16 Ks[2][64 * 64];
  __shared__ __align__(16) bf16 Vs[2][96 * 64];
  __shared__ __align__(16) bf16 Ps[4][32 * 64];
  const int tid = threadIdx.x;
  const int wave = tid >> 6, lane = tid & 63;
  const int fr = lane & 15, quad = lane >> 4;
  const int zz = blockIdx.y, z = zz & 31;
  const int e = 2 + (zz >> 5);
  const int h = z & 15, b = z >> 4;
  const long base = (long)b * 1048576 + h * 64;
  const bf16* qb = qkvb + (long)(e * 3 + 0) * 2097152 + base;
  const bf16* kb0 = qkvb + (long)(e * 3 + 1) * 2097152 + base;
  const bf16* vtb = vt23 + ((long)(e - 2) * 32 + z) * 131072;
  bf16* outp = (e == 2 ? out2 : out3) + (long)z * 131072;
  const int m0 = blockIdx.x * 128;

  // Q B-frags (constant across k-steps): B[n=qrow][k=d], k = quad*8+j+32*dk
  bfrag qf[2][2];
#pragma unroll
  for (int nf = 0; nf < 2; ++nf)
#pragma unroll
    for (int dk = 0; dk < 2; ++dk)
      qf[nf][dk] = *(const bfrag*)(qb + (long)(m0 + wave * 32 + nf * 16 + fr) * 1024 + dk * 32 + quad * 8);

  // staging: K 2 loads/thread (64 rows x 8 chunks), VT 3 loads (96 rows x 8)
  const bf16* gK[2]; int lK[2];
#pragma unroll
  for (int i = 0; i < 2; ++i) {
    int idx = i * 256 + tid;
    int r = idx >> 3, c = (idx & 7) ^ (r & 7);
    gK[i] = kb0 + (long)r * 1024 + c * 8;
    lK[i] = idx * 8;
  }
  const bf16* gV[3]; int lV[3];
#pragma unroll
  for (int i = 0; i < 3; ++i) {
    int idx = i * 256 + tid;
    int r = idx >> 3, c = (idx & 7) ^ (r & 7);
    gV[i] = vtb + (long)r * 1024 + c * 8;
    lV[i] = idx * 8;
  }
  auto stage = [&](int buf) {
#pragma unroll
    for (int i = 0; i < 2; ++i) {
      __builtin_amdgcn_global_load_lds(
          (const __attribute__((address_space(1))) void*)gK[i],
          (__attribute__((address_space(3))) void*)(Ks[buf] + lK[i]), 16, 0, 0);
      gK[i] += 64 * 1024;     // next 64 K-rows
    }
#pragma unroll
    for (int i = 0; i < 3; ++i) {
      __builtin_amdgcn_global_load_lds(
          (const __attribute__((address_space(1))) void*)gV[i],
          (__attribute__((address_space(3))) void*)(Vs[buf] + lV[i]), 16, 0, 0);
      gV[i] += 64;            // next 64 key-columns
    }
  };
  stage(0);
  stage(1);

  const int cs0 = (quad ^ (fr & 7)) * 8;
  const int cs1 = ((quad ^ 4) ^ (fr & 7)) * 8;
  bf16* myP = Ps[wave];
  ffrag av[5][2] = {};   // PV acc [d-frag][q-frag]

  for (int kt = 0; kt < 16; ++kt) {
    const int cur = kt & 1;
    if (kt < 15) asm volatile("s_waitcnt vmcnt(5)" ::: "memory");
    else         asm volatile("s_waitcnt vmcnt(0)" ::: "memory");
    __builtin_amdgcn_s_barrier();
    asm volatile("" ::: "memory");
    const bf16* kbuf = Ks[cur];
    const bf16* vbuf = Vs[cur];

    // ---- S^T[key][q] ----
    ffrag s[4][2] = {};
#pragma unroll
    for (int kf = 0; kf < 4; ++kf) {
      bfrag ka0 = *(const bfrag*)(kbuf + (kf * 16 + fr) * 64 + cs0);
      bfrag ka1 = *(const bfrag*)(kbuf + (kf * 16 + fr) * 64 + cs1);
#pragma unroll
      for (int nf = 0; nf < 2; ++nf) {
        s[kf][nf] = __builtin_amdgcn_mfma_f32_16x16x32_bf16(ka0, qf[nf][0], s[kf][nf], 0, 0, 0);
        s[kf][nf] = __builtin_amdgcn_mfma_f32_16x16x32_bf16(ka1, qf[nf][1], s[kf][nf], 0, 0, 0);
      }
    }
    // ---- P = exp(S*0.125-16) -> bf16 -> Ps[q][key] (wave-private transpose) ----
#pragma unroll
    for (int kf = 0; kf < 4; ++kf)
#pragma unroll
      for (int nf = 0; nf < 2; ++nf) {
        float e0 = __expf(s[kf][nf][0] * 0.125f - 16.f);
        float e1 = __expf(s[kf][nf][1] * 0.125f - 16.f);
        float e2 = __expf(s[kf][nf][2] * 0.125f - 16.f);
        float e3 = __expf(s[kf][nf][3] * 0.125f - 16.f);
        // C-frag: key = kf*16 + quad*4 + reg, q = nf*16 + fr; store 4 keys (8 B)
        int c2 = (kf * 2 + (quad >> 1)) ^ (fr & 7);
        uint2 w; w.x = pack2bf(e0, e1); w.y = pack2bf(e2, e3);
        *(uint2*)(myP + (nf * 16 + fr) * 64 + c2 * 8 + (quad & 1) * 4) = w;
      }
    // order the P stores (uint2) before the P reads (short8): TBAA fence +
    // DS drain (hardware DS is in-order per wave; this pins the compiler too)
    asm volatile("" ::: "memory");
    asm volatile("s_waitcnt lgkmcnt(0)" ::: "memory");
    __builtin_amdgcn_sched_barrier(0);
    // ---- PV: C[d][q] += VT x P ----
#pragma unroll
    for (int ks = 0; ks < 2; ++ks) {
      const int pcs = ks ? cs1 : cs0;
      bfrag pb[2];
#pragma unroll
      for (int nf = 0; nf < 2; ++nf)
        pb[nf] = *(const bfrag*)(myP + (nf * 16 + fr) * 64 + pcs);
#pragma unroll
      for (int ti = 0; ti < 5; ++ti) {
        bfrag va = *(const bfrag*)(vbuf + (ti * 16 + fr) * 64 + pcs);
#pragma unroll
        for (int nf = 0; nf < 2; ++nf)
          av[ti][nf] = __builtin_amdgcn_mfma_f32_16x16x32_bf16(va, pb[nf], av[ti][nf], 0, 0, 0);
      }
    }
    asm volatile("" ::: "memory");
    __builtin_amdgcn_s_barrier();
    asm volatile("" ::: "memory");
    if (kt < 14) stage(cur);
  }

  // ---- epilogue: out[q][d] (num d 0..63, den at d=64) ----
#pragma unroll
  for (int nf = 0; nf < 2; ++nf) {
    bf16* orow = outp + (long)(m0 + wave * 32 + nf * 16 + fr) * 128;
#pragma unroll
    for (int ti = 0; ti < 4; ++ti) {
      uint2 w;
      w.x = pack2bf(av[ti][nf][0], av[ti][nf][1]);
      w.y = pack2bf(av[ti][nf][2], av[ti][nf][3]);
      *(uint2*)(orow + ti * 16 + quad * 4) = w;
    }
    if (quad == 0) orow[64] = __float2bfloat16(av[4][nf][0]);
  }
}

// ---------------------------------------------------------------- prep (all weight transposes)
// grid (32, 64, 42); src[R][C] f32 -> dst[C][R] bf16, demuxed on z
__global__ void prep_k(const float* w_qkvo, const float* sub_w1, const float* sub_w2,
                       const float* conv_pw, const float* fus_w, const float* r1_w1,
                       const float* r2_w1, const float* phi_w, const float* psi_w,
                       const float* phi_b, const float* psi_b,
                       bf16* wt, bf16* fuswt, bf16* r1w1t, bf16* r2w1t,
                       bf16* phiwt, bf16* psiwt, float* phipsib, bf16* vtp1) {
  int z = blockIdx.z;
  int bx = blockIdx.x, by = blockIdx.y;
  int tx = threadIdx.x & 31, ty = threadIdx.x >> 5;
  const float* src; bf16* dst; int R, C;
  if (z < 33) {
    if (by >= 32) return;
    src = z < 16 ? w_qkvo + (long)z * 1048576
        : z < 24 ? sub_w1 + (long)(z - 16) * 1048576
        : z < 32 ? sub_w2 + (long)(z - 24) * 1048576
                 : conv_pw;
    dst = wt + (long)z * 1048576; R = 1024; C = 1024;
  } else if (z == 33) {
    src = fus_w; dst = fuswt; R = 2048; C = 1024;
  } else if (z == 34) {
    if (bx >= 16 || by >= 32) return;
    src = r1_w1; dst = r1w1t; R = 1024; C = 512;
  } else if (z < 39) {
    if (bx >= 8 || by >= 32) return;
    src = r2_w1 + (long)(z - 35) * 262144; dst = r2w1t + (long)(z - 35) * 262144;
    R = 1024; C = 256;
  } else if (z < 41) {
    if (bx >= 8 || by >= 2) return;
    src = (z == 39) ? phi_w : psi_w; dst = (z == 39) ? phiwt : psiwt; R = 64; C = 256;
  } else {
    if (by == 0) {  // ones row (performer ksum trick): slice bx of VTP1
      for (int c = threadIdx.x; c < 1024; c += 256)
        vtp1[(long)bx * 131072 + 65536 + c] = __float2bfloat16(1.0f);
    } else if (by == 1 && bx == 0) {
      for (int i = threadIdx.x; i < 512; i += 256)
        phipsib[i] = i < 256 ? phi_b[i] : psi_b[i - 256];
    }
    return;
  }
  __shared__ float t[32][33];
  int c0 = bx * 32, r0 = by * 32;
#pragma unroll
  for (int i = 0; i < 32; i += 8)
    t[ty + i][tx] = src[(long)(r0 + ty + i) * C + c0 + tx];
  __syncthreads();
#pragma unroll
  for (int i = 0; i < 32; i += 8)
    dst[(long)(c0 + ty + i) * R + r0 + tx] = __float2bfloat16(t[tx][ty + i]);
}

// per-row: x->bf16, depthwise conv, token-importance dot — one x pass
__global__ void xprep_k(const float* x, const float* dw, const float* spw, const float* spb,
                        bf16* xb, bf16* t1, float* tokimp) {
  long row = blockIdx.x;                 // 2048 rows
  int s = (int)(row & 1023);
  int tid = threadIdx.x;
  const float* xr = x + row * 1024;
  float dot = 0.f;
#pragma unroll
  for (int i = 0; i < 4; ++i) {
    int d = tid + i * 256;
    float xv = xr[d];
    xb[row * 1024 + d] = __float2bfloat16(xv);
    float a = xv * dw[1024 + d];
    if (s > 0) a += xr[d - 1024] * dw[d];
    if (s < 1023) a += xr[d + 1024] * dw[2048 + d];
    t1[row * 1024 + d] = __float2bfloat16(a);
    dot += xv * spw[d];
  }
  float tot = bred_sum(dot);
  if (tid == 0) tokimp[row] = tot + spb[0];
}

// bf16 strided [z](R x C, row stride rs) -> bf16 out + z*ldz, out[c*R + r]
__global__ void transpose_bf16_k(const bf16* in, bf16* outp, int R, int C, int rs,
                                 int inner, int inner2, long is0, long is1, long is2,
                                 long ldz) {
  __shared__ bf16 t[32][33];
  int z = blockIdx.z;
  int z0 = z % inner; int zr = z / inner;
  int z1 = zr % inner2; int z2 = zr / inner2;
  long zo = (long)z0 * is0 + (long)z1 * is1 + (long)z2 * is2;
  int c0 = blockIdx.x * 32, r0 = blockIdx.y * 32;
  int tx = threadIdx.x & 31, ty = threadIdx.x >> 5;
#pragma unroll
  for (int i = 0; i < 32; i += 8)
    t[ty + i][tx] = in[zo + (long)(r0 + ty + i) * rs + c0 + tx];
  __syncthreads();
  long ob = (long)z * ldz;
#pragma unroll
  for (int i = 0; i < 32; i += 8)
    outp[ob + (long)(c0 + ty + i) * R + r0 + tx] = t[tx][ty + i];
}

// rows 64..95 of 64 VT slices [128][1024]: row 64 = ones (denominator), 65..95 = 0
__global__ void vtinit_k(bf16* vt) {
  long i = (long)blockIdx.x * 256 + threadIdx.x;   // 64*32*1024 = 2M
  int slice = (int)(i >> 15);
  int row = 64 + (int)((i >> 10) & 31);
  int col = (int)(i & 1023);
  vt[(long)slice * 131072 + (long)row * 1024 + col] = __float2bfloat16(row == 64 ? 1.0f : 0.0f);
}

// out[((b*1024+s)*1024) + h*64 + n] = in[(h+16b)*131072 + s*128 + n] / (in[..64]+eps)
__global__ void norm_k(const bf16* in, bf16* outp, float eps) {
  int r = blockIdx.x * 4 + (threadIdx.x >> 6);   // z*1024 + s
  int n = threadIdx.x & 63;
  int z = r >> 10, s = r & 1023;
  int h = z & 15, b = z >> 4;
  const bf16* ip = in + (long)r * 128;
  float den = __bfloat162float(ip[64]) + eps;
  float v = __bfloat162float(ip[n]);
  outp[((long)(b * 1024 + s) * 1024) + h * 64 + n] = __float2bfloat16(v / den);
}

// LN + act, single global read (register cache), N <= 1024
__global__ void ln_act_k(const void* in, const float* gamma, const float* beta,
                         bf16* outp, int N, int act, int rows_per_seg, int in_bf16) {
  long row = blockIdx.x;
  int tid = threadIdx.x;
  const bf16* ib = (const bf16*)in;
  const float* iff = (const float*)in;
  float vc[4];
  float ls = 0.f;
  int i = 0;
  for (int c = tid; c < N; c += 256, ++i) {
    float v = in_bf16 ? __bfloat162float(ib[row * N + c]) : iff[row * N + c];
    vc[i] = v; ls += v;
  }
  float mean = bred_sum(ls) / N;
  float lv = 0.f;
  i = 0;
  for (int c = tid; c < N; c += 256, ++i) { float d = vc[i] - mean; lv += d * d; }
  float rstd = rsqrtf(bred_sum(lv) / N + 1e-5f);
  long go = (row / rows_per_seg) * (long)N;
  const float* gp = gamma + go;
  const float* bp = beta + go;
  i = 0;
  for (int c = tid; c < N; c += 256, ++i) {
    float v = (vc[i] - mean) * rstd * gp[c] + bp[c];
    v = act ? gelu_f(v) : fmaxf(v, 0.f);
    outp[row * N + c] = __float2bfloat16(v);
  }
}

__global__ void topk_k(const float* timp, int* outp) {
  __shared__ float vals[1024];
  __shared__ float wv[4];
  __shared__ int wi[4];
  int b = blockIdx.x, tid = threadIdx.x;
  for (int c = tid; c < 1024; c += 256) vals[c] = timp[b * 1024 + c];
  __syncthreads();
  for (int t = 0; t < 10; ++t) {
    float bv = -3.0e38f; int bi = 1 << 30;
    for (int c = tid; c < 1024; c += 256) {
      float v = vals[c];
      if (v > bv || (v == bv && c < bi)) { bv = v; bi = c; }
    }
#pragma unroll
    for (int o = 32; o > 0; o >>= 1) {
      float ov = __shfl_xor(bv, o, 64); int oi = __shfl_xor(bi, o, 64);
      if (ov > bv || (ov == bv && oi < bi)) { bv = ov; bi = oi; }
    }
    int w = tid >> 6, l = tid & 63;
    if (l == 0) { wv[w] = bv; wi[w] = bi; }
    __syncthreads();
    if (tid == 0) {
      float fv = wv[0]; int fi = wi[0];
      for (int ww = 1; ww < 4; ++ww)
        if (wv[ww] > fv || (wv[ww] == fv && wi[ww] < fi)) { fv = wv[ww]; fi = wi[ww]; }
      outp[b * 16 + t] = fi;
      vals[fi] = -3.0e38f;
    }
    __syncthreads();
  }
}

// stage-1 V column sums: 512 blocks, partials [32][16][64]
__global__ void vsum_k(const bf16* v, float* vsump) {
  __shared__ float red[4][64];
  int zz = blockIdx.x;
  int z = zz >> 4, slab = zz & 15;
  int b = z >> 4, h = z & 15;
  const bf16* vp = v + (long)b * 1048576 + h * 64;
  int d = threadIdx.x & 63, sg = threadIdx.x >> 6;
  float s = 0.f;
#pragma unroll
  for (int i = 0; i < 16; ++i) {
    int srow = slab * 64 + sg * 16 + i;
    s += __bfloat162float(vp[(long)srow * 1024 + d]);
  }
  red[sg][d] = s;
  __syncthreads();
  if (sg == 0) vsump[(long)zz * 64 + d] = red[0][d] + red[1][d] + red[2][d] + red[3][d];
}

// expert-0 sparse attention, algebraically reduced
__global__ void sparse_attn_k(const bf16* q, const bf16* k, const bf16* v,
                              const float* vsump, const int* topidx, bf16* merged) {
  __shared__ float kt[10][64], vt[10][64], vs[64], vts[64];
  int z = blockIdx.y, b = z >> 4, h = z & 15;
  int tid = threadIdx.x;
  const int* tix = topidx + b * 16;
  for (int t = tid; t < 640; t += 256) {
    int tt = t >> 6, d = t & 63;
    long src = ((long)b * 1024 + tix[tt]) * 1024 + h * 64 + d;
    kt[tt][d] = __bfloat162float(k[src]);
    vt[tt][d] = __bfloat162float(v[src]);
  }
  if (tid < 64) {
    float s = 0.f;
#pragma unroll
    for (int p = 0; p < 16; ++p) s += vsump[((long)z * 16 + p) * 64 + tid];
    vs[tid] = s;
  }
  __syncthreads();
  if (tid < 64) {
    float s = 0.f;
#pragma unroll
    for (int t = 0; t < 10; ++t) s += vt[t][tid];
    vts[tid] = s;
  }
  __syncthreads();
  int wave = tid >> 6, lane = tid & 63;
  int sq = blockIdx.x * 4 + wave;
  long qi = ((long)b * 1024 + sq) * 1024 + h * 64 + lane;
  float qd = __bfloat162float(q[qi]);
  float sc[10];
#pragma unroll
  for (int t = 0; t < 10; ++t) sc[t] = wred_sum(qd * kt[t][lane]) * 0.125f;
  float m = 0.f;
#pragma unroll
  for (int t = 0; t < 10; ++t) m = fmaxf(m, sc[t]);
  float e[10], se = 0.f;
#pragma unroll
  for (int t = 0; t < 10; ++t) { e[t] = __expf(sc[t] - m); se += e[t]; }
  float em = __expf(-m);
  float Z = 1014.f * em + se;
  float o = em * (vs[lane] - vts[lane]);
#pragma unroll
  for (int t = 0; t < 10; ++t) o += e[t] * vt[t][lane];
  merged[qi] = __float2bfloat16(o / Z);
}

__global__ void router1_k(const bf16* h1, const float* w, const float* bias, float* outp) {
  int row = blockIdx.x * 4 + (threadIdx.x >> 6);
  int l = threadIdx.x & 63;
  const bf16* hp = h1 + (long)row * 512;
  float a0 = 0, a1 = 0, a2 = 0, a3 = 0;
  for (int c = l; c < 512; c += 64) {
    float hv = __bfloat162float(hp[c]);
    const float* wp = w + c * 4;
    a0 += hv * wp[0]; a1 += hv * wp[1]; a2 += hv * wp[2]; a3 += hv * wp[3];
  }
  a0 = wred_sum(a0); a1 = wred_sum(a1); a2 = wred_sum(a2); a3 = wred_sum(a3);
  a0 += bias[0]; a1 += bias[1]; a2 += bias[2]; a3 += bias[3];
  float m = fmaxf(fmaxf(a0, a1), fmaxf(a2, a3));
  float e0 = __expf(a0 - m), e1 = __expf(a1 - m), e2 = __expf(a2 - m), e3 = __expf(a3 - m);
  float inv = 1.f / (e0 + e1 + e2 + e3);
  if (l == 0) {
    float* op = outp + (long)row * 4;
    op[0] = e0 * inv; op[1] = e1 * inv; op[2] = e2 * inv; op[3] = e3 * inv;
  }
}

__global__ void router2_k(const bf16* h2, const float* w, const float* bias, float* outp,
                          int rows_per_seg) {
  int row = blockIdx.x * 4 + (threadIdx.x >> 6);
  int l = threadIdx.x & 63;
  int seg = row / rows_per_seg;
  const float* wp = w + (long)seg * 512;
  const float* bp = bias + (long)seg * 2;
  const bf16* hp = h2 + (long)row * 256;
  float a0 = 0, a1 = 0;
  for (int c = l; c < 256; c += 64) {
    float hv = __bfloat162float(hp[c]);
    a0 += hv * wp[c * 2]; a1 += hv * wp[c * 2 + 1];
  }
  a0 = wred_sum(a0); a1 = wred_sum(a1);
  a0 += bp[0]; a1 += bp[1];
  float m = fmaxf(a0, a1);
  float e0 = __expf(a0 - m), e1 = __expf(a1 - m);
  float inv = 1.f / (e0 + e1);
  if (l == 0) { outp[(long)row * 2] = e0 * inv; outp[(long)row * 2 + 1] = e1 * inv; }
}

// final: out[m,n] = sum_z p1[m][z/2] * p2[z/2][m][z&1] * part[z][m][n]
__global__ void combine_k(const bf16* part, const float* p1, const float* p2, float* outp) {
  long i = (long)blockIdx.x * 256 + threadIdx.x;
  long m = i >> 10;
  float acc = 0.f;
#pragma unroll
  for (int zz = 0; zz < 8; ++zz) {
    int e = zz >> 1, j = zz & 1;
    float w = p1[m * 4 + e] * p2[(long)e * 4096 + m * 2 + j];
    acc += w * __bfloat162float(part[(long)zz * 2097152 + i]);
  }
  outp[i] = acc;
}

// ---------------------------------------------------------------- host
extern "C" void kernel_launch(void* const* d_in, const int* in_sizes, int n_in,
                              void* d_out, int out_size, void* d_ws, size_t ws_size,
                              hipStream_t stream) {
  const float* x = (const float*)d_in[0];
  const float* w_qkvo = (const float*)d_in[1];
  const float* b_qkvo = (const float*)d_in[2];
  const float* sp_w = (const float*)d_in[3];
  const float* sp_b = (const float*)d_in[4];
  const float* phi_w = (const float*)d_in[5];
  const float* phi_b = (const float*)d_in[6];
  const float* psi_w = (const float*)d_in[7];
  const float* psi_b = (const float*)d_in[8];
  const float* conv_dw = (const float*)d_in[9];
  const float* conv_pw = (const float*)d_in[10];
  const float* fus_w = (const float*)d_in[11];
  const float* fus_b = (const float*)d_in[12];
  const float* sub_w1 = (const float*)d_in[13];
  const float* sub_b1 = (const float*)d_in[14];
  const float* sub_g = (const float*)d_in[15];
  const float* sub_be = (const float*)d_in[16];
  const float* sub_w2 = (const float*)d_in[17];
  const float* sub_b2 = (const float*)d_in[18];
  const float* r1_w1 = (const float*)d_in[19];
  const float* r1_b1 = (const float*)d_in[20];
  const float* r1_g = (const float*)d_in[21];
  const float* r1_be = (const float*)d_in[22];
  const float* r1_w2 = (const float*)d_in[23];
  const float* r1_b2 = (const float*)d_in[24];
  const float* r2_w1 = (const float*)d_in[25];
  const float* r2_b1 = (const float*)d_in[26];
  const float* r2_g = (const float*)d_in[27];
  const float* r2_be = (const float*)d_in[28];
  const float* r2_w2 = (const float*)d_in[29];
  const float* r2_b2 = (const float*)d_in[30];
  (void)in_sizes; (void)n_in; (void)ws_size; (void)out_size;

  char* ws = (char*)d_ws;
  size_t off = 0;
  auto take = [&](size_t bytes) { void* p = ws + off; off += (bytes + 255) & ~(size_t)255; return p; };

  const long EL2M = 2097152;  // 2048*1024
  const long EL1M = 1048576;  // 1024*1024

  bf16* XB      = (bf16*)take((size_t)EL2M * 2);
  bf16* WQKVOT  = (bf16*)take((size_t)16 * EL1M * 2);
  bf16* SUBW1T  = (bf16*)take((size_t)8 * EL1M * 2);
  bf16* SUBW2T  = (bf16*)take((size_t)8 * EL1M * 2);
  bf16* CONVPWT = (bf16*)take((size_t)EL1M * 2);
  bf16* FUSWT   = (bf16*)take((size_t)EL2M * 2);
  bf16* R1W1T   = (bf16*)take((size_t)512 * 1024 * 2);
  bf16* R2W1T   = (bf16*)take((size_t)4 * 256 * 1024 * 2);
  bf16* PHIWT   = (bf16*)take((size_t)16384 * 2);
  bf16* PSIWT   = (bf16*)take((size_t)16384 * 2);
  float* PHIPSIB = (float*)take((size_t)512 * 4);
  bf16* QKVB    = (bf16*)take((size_t)12 * EL2M * 2);  // + MERGED4 adjacent -> sub arena
  bf16* MERGED4 = (bf16*)take((size_t)4 * EL2M * 2);
  bf16* VTP1    = (bf16*)take((size_t)32 * 128 * 1024 * 2);  // performer TNUM / e3 attn TNUM
  bf16* EO      = (bf16*)take((size_t)4 * EL2M * 2);
  bf16* T1      = (bf16*)take((size_t)EL2M * 2);       // survives attention phase
  bf16* ARENA   = (bf16*)take((size_t)64 * 1024 * 1024);
  float* PROBS1 = (float*)take((size_t)2048 * 4 * 4);
  float* PROBS2 = (float*)take((size_t)4 * 2048 * 2 * 4);
  float* TOKIMP = (float*)take((size_t)2048 * 4);
  int*   TOPIDX = (int*)take((size_t)2 * 16 * 4);
  float* VSUMP  = (float*)take((size_t)32 * 16 * 64 * 4);

  // ARENA phase 1 (performer):
  bf16* QPHI  = ARENA;                       // [32][1024][256]
  bf16* KPSI  = ARENA + 8388608;             // [32][1024][256]
  bf16* KPSIT = ARENA + 16777216;            // [32][256][1024]
  bf16* KVTX  = ARENA + 25165824;            // [32][128][256] (row64 = ksum)
  // ARENA phase 3 (late):
  bf16* SUB2F = ARENA;                       // [8][2048][1024] bf16 partials
  float* F32TMP = (float*)(ARENA + 16777216);  // 8 MB
  bf16* H1 = ARENA + 20971520;               // [2048][512]
  bf16* H2 = ARENA + 22020096;               // [4*2048][256]
  bf16* AO = ARENA + 24117248;               // [2048][1024]
  bf16* XC = ARENA + 26214400;               // [2048][1024]
  // QKVB slice reuse (dead after sparse/performer phases):
  bf16* TNUM23 = QKVB;                       // slices 0-1: e2 attn [32][1024][128] num+den
  bf16* VT23   = QKVB + 2 * EL2M;            // slices 2-5: [64][128][1024] V^T (+ones row 64)
  // sub arena (aliases QKVB+MERGED4, dead by then):
  bf16* SUB1A = QKVB;                        // [8][2048][1024]
  bf16* SUB1B = QKVB + 16777216;             // [8][2048][1024]

  // ---- phase 0: weights + x prep ----
  prep_k<<<dim3(32, 64, 42), 256, 0, stream>>>(w_qkvo, sub_w1, sub_w2, conv_pw, fus_w,
                                               r1_w1, r2_w1, phi_w, psi_w, phi_b, psi_b,
                                               WQKVOT, FUSWT, R1W1T, R2W1T,
                                               PHIWT, PSIWT, PHIPSIB, VTP1);
  xprep_k<<<2048, 256, 0, stream>>>(x, conv_dw, sp_w, sp_b, XB, T1, TOKIMP);

  // ---- QKV for all experts, one batch-12 GEMM (128x256, 768 blocks = 3.0 rounds) ----
  {
    GemmP g = gp0();
    g.A = XB; g.lda = 1024;
    g.B = WQKVOT; g.ldb = 1024; g.sB0 = EL1M; g.sB1 = 4 * EL1M;
    g.C = QKVB; g.ldc = 1024; g.sC0 = EL2M; g.sC1 = 3 * EL2M;
    g.bias = b_qkvo; g.sb0 = 1024; g.sb1 = 4096;
    g.K = 1024; g.inner = 3; g.mode = 0;
    launch_gemm8(stream, 1, 2048, 1024, 12, g);
  }

  // ---- expert 0: sparse attention ----
  topk_k<<<2, 256, 0, stream>>>(TOKIMP, TOPIDX);
  vsum_k<<<512, 256, 0, stream>>>(QKVB + 2 * EL2M, VSUMP);
  sparse_attn_k<<<dim3(256, 32), 256, 0, stream>>>(QKVB, QKVB + EL2M, QKVB + 2 * EL2M,
                                                   VSUMP, TOPIDX, MERGED4);

  // ---- expert 1: performer ----
  {  // phi(Q) and psi(K) in one batch-64 GEMM
    GemmP g = gp0();
    g.A = QKVB + 3 * EL2M; g.lda = 1024; g.sA0 = 64; g.sA1 = EL1M;
    g.B = PHIWT; g.ldb = 64; g.sB1 = 16384; g.zBshift = 1;
    g.C = QPHI; g.ldc = 256; g.sC0 = 262144; g.sC1 = 16 * 262144L;
    g.bias = PHIPSIB; g.sb1 = 256;
    g.K = 64; g.inner = 16; g.mode = 4;
    launch_gemm(stream, 2, 1024, 256, 64, g);
  }
  transpose_bf16_k<<<dim3(8, 32, 32), 256, 0, stream>>>(KPSI, KPSIT, 1024, 256, 256,
                                                        32, 1, 262144, 0, 0, 262144);
  transpose_bf16_k<<<dim3(2, 32, 32), 256, 0, stream>>>(QKVB + 5 * EL2M, VTP1, 1024, 64, 1024,
                                                        16, 2, 64, EL1M, 0, 131072);
  {  // KVTX[m,d] = sum_l VTP1[m,l]*KPSIT[d,l]; row 64 = ksum
    GemmP g = gp0();
    g.A = VTP1; g.lda = 1024; g.sA0 = 131072; g.sA1 = 16 * 131072L;
    g.B = KPSIT; g.ldb = 1024; g.sB0 = 262144; g.sB1 = 16 * 262144L;
    g.C = KVTX; g.ldc = 256; g.sC0 = 32768; g.sC1 = 16 * 32768L;
    g.K = 1024; g.inner = 16; g.mode = 0;
    launch_gemm(stream, 2, 128, 256, 32, g);
  }
  {  // num+den: N=128 against KVTX (col 64 = qphi.ksum) -> TNUM (aliases VTP1)
    GemmP g = gp0();
    g.A = QPHI; g.lda = 256; g.sA0 = 262144; g.sA1 = 16 * 262144L;
    g.B = KVTX; g.ldb = 256; g.sB0 = 32768; g.sB1 = 16 * 32768L;
    g.C = VTP1; g.ldc = 128; g.sC0 = 131072; g.sC1 = 16 * 131072L;
    g.K = 256; g.inner = 16; g.mode = 0;
    launch_gemm(stream, 2, 1024, 128, 32, g);
  }
  norm_k<<<8192, 256, 0, stream>>>(VTP1, MERGED4 + EL2M, 1e-8f);

  // ---- V^T (+ones/zeros rows) for experts 2,3 into dead QKVB slices 2-5 ----
  transpose_bf16_k<<<dim3(2, 32, 64), 256, 0, stream>>>(QKVB + 8 * EL2M, VT23, 1024, 64, 1024,
                                                        16, 2, 64, EL1M, 3 * EL2M, 131072);
  vtinit_k<<<8192, 256, 0, stream>>>(VT23);

  // ---- experts 2 & 3: fused attention (exp(s-16) softmax, no SC materialization) ----
  fused_attn_k<<<dim3(8, 64), 256, 0, stream>>>(QKVB, VT23, TNUM23, VTP1);
  norm_k<<<8192, 256, 0, stream>>>(TNUM23, MERGED4 + 2 * EL2M, 0.f);
  norm_k<<<8192, 256, 0, stream>>>(VTP1, MERGED4 + 3 * EL2M, 0.f);

  // ---- batch-4 output projection (z=3 -> AO), 128x256 (256 blocks = 1.0 round) ----
  {
    GemmP g = gp0();
    g.A = MERGED4; g.lda = 1024; g.sA1 = EL2M;
    g.B = WQKVOT + 3 * EL1M; g.ldb = 1024; g.sB1 = 4 * EL1M;
    g.C = EO; g.ldc = 1024; g.sC1 = EL2M;
    g.C2 = AO; g.c2z = 3;
    g.bias = b_qkvo + 3 * 1024; g.sb1 = 4096;
    g.K = 1024; g.mode = 0;
    launch_gemm8(stream, 1, 2048, 1024, 4, g);
  }

  // ---- conv branch + fusion ----
  {
    GemmP g = gp0();
    g.A = T1; g.lda = 1024;
    g.B = CONVPWT; g.ldb = 1024;
    g.C = XC; g.ldc = 1024;
    g.K = 1024; g.mode = 3;
    launch_gemm(stream, 2, 2048, 1024, 1, g);
  }
  {  // fusion: A = [AO | XC], K=2048 (SPLIT variant)
    GemmP g = gp0();
    g.A = AO; g.A2 = XC; g.kSplit = 1024; g.lda = 1024;
    g.B = FUSWT; g.ldb = 2048;
    g.C = EO + 3 * EL2M; g.ldc = 1024;
    g.bias = fus_b; g.K = 2048; g.mode = 0;
    launch_gemm(stream, 3, 2048, 1024, 1, g);
  }

  // ---- routers ----
  {
    GemmP g = gp0();
    g.A = XB; g.lda = 1024;
    g.B = R1W1T; g.ldb = 1024;
    g.C = F32TMP; g.ldc = 512;
    g.bias = r1_b1; g.K = 1024; g.mode = 1;
    launch_gemm(stream, 2, 2048, 512, 1, g);
  }
  ln_act_k<<<2048, 256, 0, stream>>>(F32TMP, r1_g, r1_be, H1, 512, 0, 2048, 0);
  router1_k<<<512, 256, 0, stream>>>(H1, r1_w2, r1_b2, PROBS1);
  {
    GemmP g = gp0();
    g.A = EO; g.lda = 1024; g.sA1 = EL2M;
    g.B = R2W1T; g.ldb = 1024; g.sB1 = 262144;
    g.C = F32TMP; g.ldc = 256; g.sC1 = 2048 * 256;
    g.bias = r2_b1; g.sb1 = 256; g.K = 1024; g.mode = 1;
    launch_gemm(stream, 2, 2048, 256, 4, g);
  }
  ln_act_k<<<8192, 256, 0, stream>>>(F32TMP, r2_g, r2_be, H2, 256, 0, 2048, 0);
  router2_k<<<2048, 256, 0, stream>>>(H2, r2_w2, r2_b2, PROBS2, 2048);

  // ---- sub-experts: batch-8 everything (256x256, 256 blocks = 1.0 round) ----
  {  // sub1: z = j + 2*i
    GemmP g = gp0();
    g.A = EO; g.lda = 1024; g.sA1 = EL2M;
    g.B = SUBW1T; g.ldb = 1024; g.sB0 = EL1M; g.sB1 = 2 * EL1M;
    g.C = SUB1A; g.ldc = 1024; g.sC0 = EL2M; g.sC1 = 2 * EL2M;
    g.bias = sub_b1; g.sb0 = 1024; g.sb1 = 2048;
    g.K = 1024; g.inner = 2; g.mode = 0;
    launch_gemm8(stream, 0, 2048, 1024, 8, g);
  }
  ln_act_k<<<16384, 256, 0, stream>>>(SUB1A, sub_g, sub_be, SUB1B, 1024, 1, 2048, 1);
  {  // sub2 partials (bias folded)
    GemmP g = gp0();
    g.A = SUB1B; g.lda = 1024; g.sA1 = EL2M;
    g.B = SUBW2T; g.ldb = 1024; g.sB1 = EL1M;
    g.C = SUB2F; g.ldc = 1024; g.sC1 = EL2M;
    g.bias = sub_b2; g.sb1 = 1024;
    g.K = 1024; g.mode = 0;
    launch_gemm8(stream, 0, 2048, 1024, 8, g);
  }
  combine_k<<<8192, 256, 0, stream>>>(SUB2F, PROBS1, PROBS2, (float*)d_out);
}